// Round 3
// baseline (2541.132 us; speedup 1.0000x reference)
//
#include <hip/hip_runtime.h>

#define NN 50000
#define EE 800000
#define IND 128
#define NCOL 1024
#define KM 320            // K * Mpad = 10*32
#define M30 30
#define RATIO 0.1825741858f   // 30^-0.5
#define EPSF 1e-6f
#define QKSCALE 0.7071067812f // (1/sqrt(0.25)) * 64^-0.25

__device__ __forceinline__ unsigned f2s(float f) {
    unsigned u = __float_as_uint(f);
    return (u & 0x80000000u) ? ~u : (u | 0x80000000u);
}
__device__ __forceinline__ float s2f(unsigned s) {
    return __uint_as_float((s & 0x80000000u) ? (s & 0x7fffffffu) : ~s);
}

// ---------- prep: Wt[IND][NCOL] (cols: 0-255 s*Wq^T, 256-511 s*Wk^T, 512-767 Wv^T,
// 768-895 Pq[h,m], 896-1023 Pk[h,m]), bias_ext[NCOL], WoT[256][64]
__global__ void k_prep(const float* __restrict__ Wq, const float* __restrict__ Wqb,
                       const float* __restrict__ Wk, const float* __restrict__ Wkb,
                       const float* __restrict__ Wv, const float* __restrict__ Wvb,
                       const float* __restrict__ Wo, const float* __restrict__ proj,
                       float* __restrict__ Wt, float* __restrict__ bext, float* __restrict__ WoT) {
    int i = blockIdx.x;   // 0..127
    int t = threadIdx.x;  // 0..255
    Wt[i*NCOL + t]       = QKSCALE * Wq[t*IND + i];
    Wt[i*NCOL + 256 + t] = QKSCALE * Wk[t*IND + i];
    Wt[i*NCOL + 512 + t] = Wv[t*IND + i];
    {
        const float* W = (t < 128) ? Wq : Wk;
        int c = (t < 128) ? t : (t - 128);
        int h = c >> 5, m = c & 31;
        float val = 0.f;
        if (m < M30) {
            for (int d = 0; d < 64; ++d)
                val += QKSCALE * W[(h*64+d)*IND + i] * proj[m*64 + d];
        }
        Wt[i*NCOL + 768 + t] = val;
    }
    if (t < 128) {
        int f = i*2 + (t >> 6);
        int o = t & 63;
        WoT[f*64 + o] = Wo[o*256 + f];
    }
    if (i == 0) {
        bext[t]       = QKSCALE * Wqb[t];
        bext[256 + t] = QKSCALE * Wkb[t];
        bext[512 + t] = Wvb[t];
        const float* Bb = (t < 128) ? Wqb : Wkb;
        int c = (t < 128) ? t : (t - 128);
        int h = c >> 5, m = c & 31;
        float val = 0.f;
        if (m < M30) {
            for (int d = 0; d < 64; ++d)
                val += QKSCALE * Bb[h*64+d] * proj[m*64 + d];
        }
        bext[768 + t] = val;
    }
}

// ---------- fused QKV + dash GEMM + feature maps. 16 nodes per block.
__global__ __launch_bounds__(256) void k_qkv(const float* __restrict__ z, const float* __restrict__ Wt,
                      const float* __restrict__ bext,
                      float* __restrict__ vbuf, float* __restrict__ qp, float* __restrict__ kpb,
                      unsigned* __restrict__ stab) {
    __shared__ float zl[IND][16];
    __shared__ float diag[16][2][4];
    int t = threadIdx.x;
    int n0 = blockIdx.x * 16;
    #pragma unroll
    for (int ss = 0; ss < 2; ++ss) {
        int s = t + ss*256;
        int node = s >> 5;
        int ii = (s & 31) * 4;
        float4 zv = *(const float4*)(z + (size_t)(n0+node)*IND + ii);
        zl[ii+0][node] = zv.x; zl[ii+1][node] = zv.y; zl[ii+2][node] = zv.z; zl[ii+3][node] = zv.w;
    }
    __syncthreads();
    float aq[16], ak[16], av[16], ad[16];
    {
        float ba = bext[t], bb = bext[256+t], bc = bext[512+t], bd = bext[768+t];
        #pragma unroll
        for (int j = 0; j < 16; ++j) { aq[j]=ba; ak[j]=bb; av[j]=bc; ad[j]=bd; }
    }
    for (int i = 0; i < IND; ++i) {
        float wa = Wt[i*NCOL + t];
        float wb = Wt[i*NCOL + 256 + t];
        float wc = Wt[i*NCOL + 512 + t];
        float wd = Wt[i*NCOL + 768 + t];
        const float4* zr = (const float4*)(&zl[i][0]);
        float zz[16];
        #pragma unroll
        for (int c = 0; c < 4; ++c) {
            float4 zv = zr[c];
            zz[c*4+0]=zv.x; zz[c*4+1]=zv.y; zz[c*4+2]=zv.z; zz[c*4+3]=zv.w;
        }
        #pragma unroll
        for (int j = 0; j < 16; ++j) {
            aq[j] = fmaf(zz[j], wa, aq[j]);
            ak[j] = fmaf(zz[j], wb, ak[j]);
            av[j] = fmaf(zz[j], wc, av[j]);
            ad[j] = fmaf(zz[j], wd, ad[j]);
        }
    }
    int wv_ = t >> 6;
    #pragma unroll
    for (int j = 0; j < 16; ++j) {
        float sq = aq[j]*aq[j];
        float sk = ak[j]*ak[j];
        #pragma unroll
        for (int off = 32; off >= 1; off >>= 1) {
            sq += __shfl_xor(sq, off, 64);
            sk += __shfl_xor(sk, off, 64);
        }
        if ((t & 63) == 0) { diag[j][0][wv_] = 0.5f*sq; diag[j][1][wv_] = 0.5f*sk; }
    }
    #pragma unroll
    for (int j = 0; j < 16; ++j) vbuf[(size_t)(n0+j)*256 + t] = av[j];
    __syncthreads();
    if (t < 128) {
        int h = t >> 5, m = t & 31;
        bool valid = (m < M30);
        #pragma unroll
        for (int j = 0; j < 16; ++j) {
            float dq = ad[j];
            float mx = valid ? dq : -3.0e38f;
            #pragma unroll
            for (int off = 16; off >= 1; off >>= 1)
                mx = fmaxf(mx, __shfl_xor(mx, off, 32));
            float val = 0.f;
            if (valid) val = RATIO * (__expf(dq - diag[j][0][h] - mx) + EPSF);
            qp[(size_t)(n0+j)*128 + t] = val;
        }
    } else {
        int tt = t - 128;
        int h = tt >> 5, m = tt & 31;
        bool valid = (m < M30);
        float bm = -3.0e38f;
        #pragma unroll
        for (int j = 0; j < 16; ++j) {
            float dk = ad[j];
            kpb[(size_t)(n0+j)*128 + tt] = valid ? (dk - diag[j][1][h]) : 0.f;
            if (valid) bm = fmaxf(bm, dk);
        }
        #pragma unroll
        for (int off = 16; off >= 1; off >>= 1)
            bm = fmaxf(bm, __shfl_xor(bm, off, 32));
        if ((tt & 31) == 0) atomicMax(&stab[h], f2s(bm));
    }
}

__global__ void k_deg(const int* __restrict__ ei, int* __restrict__ din, int* __restrict__ dout) {
    int e = blockIdx.x*256 + threadIdx.x;
    if (e < EE) {
        atomicAdd(&dout[ei[e]], 1);
        atomicAdd(&din[ei[EE + e]], 1);
    }
}

// rsdout[n] = dout>0 ? rsqrt(dout) : 0
__global__ void k_rs(const int* __restrict__ dout, float* __restrict__ rsd) {
    int i = blockIdx.x*256 + threadIdx.x;
    if (i < NN) {
        int d = dout[i];
        rsd[i] = d > 0 ? rsqrtf((float)d) : 0.f;
    }
}

// ---------- prefix sum over din (3-kernel scan) ----------
__global__ void k_scan_part(const int* __restrict__ din, int* __restrict__ bsum) {
    __shared__ int red[256];
    int t = threadIdx.x;
    int i = blockIdx.x*256 + t;
    red[t] = (i < NN) ? din[i] : 0;
    __syncthreads();
    for (int off = 128; off >= 1; off >>= 1) {
        if (t < off) red[t] += red[t+off];
        __syncthreads();
    }
    if (t == 0) bsum[blockIdx.x] = red[0];
}
__global__ void k_scan_top(const int* __restrict__ bsum, int* __restrict__ boff) {
    if (threadIdx.x == 0) {
        int acc = 0;
        for (int b = 0; b < 196; ++b) { boff[b] = acc; acc += bsum[b]; }
    }
}
__global__ void k_scan_fin(const int* __restrict__ din, const int* __restrict__ boff,
                           int* __restrict__ offsets, int* __restrict__ cursor) {
    __shared__ int s[256];
    int t = threadIdx.x;
    int i = blockIdx.x*256 + t;
    int v = (i < NN) ? din[i] : 0;
    s[t] = v;
    __syncthreads();
    for (int off = 1; off < 256; off <<= 1) {
        int add = (t >= off) ? s[t-off] : 0;
        __syncthreads();
        s[t] += add;
        __syncthreads();
    }
    int excl = s[t] - v + boff[blockIdx.x];
    if (i < NN) { offsets[i] = excl; cursor[i] = excl; }
    if (i == NN-1) offsets[NN] = excl + v;
}

// scatter edge rows into CSR-by-col order
__global__ void k_scatter(const int* __restrict__ ei, int* __restrict__ cursor,
                          int* __restrict__ csr_row) {
    int e = blockIdx.x*256 + threadIdx.x;
    if (e < EE) {
        int col = ei[EE + e];
        int pos = atomicAdd(&cursor[col], 1);
        csr_row[pos] = ei[e];
    }
}

// ---------- finish kp = ratio*(exp(dash-diag-stab)+eps) in place; accumulate kp_sum[h][m]
__global__ void k_kp(float* __restrict__ kpb, const unsigned* __restrict__ stab,
                     float* __restrict__ kp_sum) {
    __shared__ float red[256];
    int t = threadIdx.x;
    int hm = t & 127;
    int h = hm >> 5, m = hm & 31;
    float st = s2f(stab[h]);
    float ksum = 0.f;
    const int total = NN*128;
    for (int idx = blockIdx.x*256 + t; idx < total; idx += gridDim.x*256) {
        float val = kpb[idx];
        float kpv = 0.f;
        if (m < M30) kpv = RATIO * (__expf(val - st) + EPSF);
        kpb[idx] = kpv;
        ksum += kpv;
    }
    red[t] = ksum;
    __syncthreads();
    if (t < 128) atomicAdd(&kp_sum[hm], red[t] + red[t+128]);
}

// ---------- kvs[h][km][d] = sum_n (kp[n,m]*e^g[n,k]) * v[n,d]; ktg[h][km] = sum_n w
// 500 blocks (125 x 4 heads), 400 nodes/block, 16-node double-buffered tiles.
// Thread (mg=t&15, dg=t>>4): owns m in {2mg,2mg+1}, d in {4dg..4dg+3}, all 10 k.
__global__ __launch_bounds__(256, 2) void k_kvs(const float* __restrict__ kpb,
                      const float* __restrict__ g, const float* __restrict__ vbuf,
                      float* __restrict__ kvs, float* __restrict__ ktg) {
    __shared__ float kp_l[2][16][32];
    __shared__ float eg_l[2][10][16];
    __shared__ float v_l[2][16][64];
    int t = threadIdx.x;
    int h = blockIdx.y;
    int n0 = blockIdx.x * 400;
    int mg = t & 15, dg = t >> 4;
    int snode = t >> 4, smp = t & 15;
    float acc[2][10][4];
    float wsum[2][10];
    #pragma unroll
    for (int a = 0; a < 2; ++a) {
        #pragma unroll
        for (int k = 0; k < 10; ++k) {
            wsum[a][k] = 0.f;
            #pragma unroll
            for (int b = 0; b < 4; ++b) acc[a][k][b] = 0.f;
        }
    }
    // stage tile 0
    {
        float2 k2 = *(const float2*)(kpb + (size_t)(n0 + snode)*128 + h*32 + smp*2);
        kp_l[0][snode][smp*2] = k2.x; kp_l[0][snode][smp*2+1] = k2.y;
        float4 vv = *(const float4*)(vbuf + (size_t)(n0 + snode)*256 + h*64 + smp*4);
        *(float4*)&v_l[0][snode][smp*4] = vv;
        if (t < 160) {
            int nj = t / 10, kk = t % 10;
            eg_l[0][kk][nj] = __expf(g[(size_t)(n0 + nj)*40 + h*10 + kk]);
        }
    }
    __syncthreads();
    for (int it = 0; it < 25; ++it) {
        int cur = it & 1;
        // issue next-tile global loads into regs (latency hides under compute)
        float2 s_kp = make_float2(0.f, 0.f);
        float4 s_v = make_float4(0.f, 0.f, 0.f, 0.f);
        float s_eg = 0.f;
        if (it + 1 < 25) {
            int nb = n0 + (it+1)*16;
            s_kp = *(const float2*)(kpb + (size_t)(nb + snode)*128 + h*32 + smp*2);
            s_v  = *(const float4*)(vbuf + (size_t)(nb + snode)*256 + h*64 + smp*4);
            if (t < 160) s_eg = g[(size_t)(nb + t/10)*40 + h*10 + (t%10)];
        }
        // compute on current tile, 8 nodes at a time (register-blocked)
        #pragma unroll
        for (int jh = 0; jh < 2; ++jh) {
            float2 kp2[8]; float4 v4[8];
            #pragma unroll
            for (int j = 0; j < 8; ++j) {
                kp2[j] = *(const float2*)&kp_l[cur][jh*8 + j][mg*2];
                v4[j]  = *(const float4*)&v_l[cur][jh*8 + j][dg*4];
            }
            #pragma unroll
            for (int k = 0; k < 10; ++k) {
                float4 ea = *(const float4*)&eg_l[cur][k][jh*8];
                float4 eb = *(const float4*)&eg_l[cur][k][jh*8 + 4];
                float eg8[8] = {ea.x, ea.y, ea.z, ea.w, eb.x, eb.y, eb.z, eb.w};
                #pragma unroll
                for (int j = 0; j < 8; ++j) {
                    float w0 = kp2[j].x * eg8[j];
                    float w1 = kp2[j].y * eg8[j];
                    wsum[0][k] += w0;
                    wsum[1][k] += w1;
                    acc[0][k][0] = fmaf(w0, v4[j].x, acc[0][k][0]);
                    acc[0][k][1] = fmaf(w0, v4[j].y, acc[0][k][1]);
                    acc[0][k][2] = fmaf(w0, v4[j].z, acc[0][k][2]);
                    acc[0][k][3] = fmaf(w0, v4[j].w, acc[0][k][3]);
                    acc[1][k][0] = fmaf(w1, v4[j].x, acc[1][k][0]);
                    acc[1][k][1] = fmaf(w1, v4[j].y, acc[1][k][1]);
                    acc[1][k][2] = fmaf(w1, v4[j].z, acc[1][k][2]);
                    acc[1][k][3] = fmaf(w1, v4[j].w, acc[1][k][3]);
                }
            }
        }
        // write staged tile
        if (it + 1 < 25) {
            int nxt = cur ^ 1;
            kp_l[nxt][snode][smp*2] = s_kp.x; kp_l[nxt][snode][smp*2+1] = s_kp.y;
            *(float4*)&v_l[nxt][snode][smp*4] = s_v;
            if (t < 160) eg_l[nxt][t % 10][t / 10] = __expf(s_eg);
        }
        __syncthreads();
    }
    float* kb = kvs + h*KM*64;
    #pragma unroll
    for (int a = 0; a < 2; ++a)
        #pragma unroll
        for (int k = 0; k < 10; ++k)
            #pragma unroll
            for (int b = 0; b < 4; ++b)
                atomicAdd(&kb[(k*32 + mg*2 + a)*64 + dg*4 + b], acc[a][k][b]);
    if (dg == 0) {
        #pragma unroll
        for (int a = 0; a < 2; ++a)
            #pragma unroll
            for (int k = 0; k < 10; ++k)
                atomicAdd(&ktg[h*KM + k*32 + mg*2 + a], wsum[a][k]);
    }
}

// ---------- per node: norm/qpn (in place), z_den per k, z_next = mean_k(num/den)
__global__ __launch_bounds__(256) void k_znext(float* __restrict__ qp, const float* __restrict__ kvs,
                        const float* __restrict__ ktg, const float* __restrict__ kp_sum,
                        float* __restrict__ znext) {
    int t = threadIdx.x;
    int n = blockIdx.x*256 + t;
    int h = blockIdx.y;
    if (n >= NN) return;
    float q[32];
    float* qb = qp + (size_t)n*128 + h*32;
    #pragma unroll
    for (int c = 0; c < 8; ++c) {
        float4 v4 = *(const float4*)(qb + c*4);
        q[c*4+0]=v4.x; q[c*4+1]=v4.y; q[c*4+2]=v4.z; q[c*4+3]=v4.w;
    }
    const float* ks = kp_sum + h*32;
    float norm = 0.f;
    #pragma unroll
    for (int m = 0; m < 32; ++m) norm = fmaf(q[m], ks[m], norm);
    float rn = 1.f / norm;
    #pragma unroll
    for (int c = 0; c < 8; ++c) {
        float4 v4 = make_float4(q[c*4+0]*rn, q[c*4+1]*rn, q[c*4+2]*rn, q[c*4+3]*rn);
        *(float4*)(qb + c*4) = v4;
    }
    const float* kvh = kvs + h*KM*64;
    const float* kth = ktg + h*KM;
    float* zo = znext + (size_t)n*256 + h*64;
    for (int dc = 0; dc < 4; ++dc) {
        float ms[16];
        #pragma unroll
        for (int d = 0; d < 16; ++d) ms[d] = 0.f;
        for (int k = 0; k < 10; ++k) {
            float den = 0.f;
            #pragma unroll
            for (int m = 0; m < 32; ++m) den = fmaf(q[m], kth[k*32+m], den);
            float rd = 1.f / (den * 10.f);
            const float* base = kvh + k*2048 + dc*16;
            #pragma unroll
            for (int m = 0; m < 32; ++m) {
                float qm = q[m] * rd;
                #pragma unroll
                for (int d = 0; d < 16; ++d)
                    ms[d] = fmaf(qm, base[m*64 + d], ms[d]);
            }
        }
        #pragma unroll
        for (int d = 0; d < 16; ++d) zo[dc*16 + d] = ms[d];
    }
}

// ---------- A[e,h] = dot32(qpn[end], kp[start])
__global__ void k_edge(const int* __restrict__ ei, const float* __restrict__ qpn,
                       const float* __restrict__ kpb, float* __restrict__ A) {
    int gid = blockIdx.x*256 + threadIdx.x;
    int e = gid >> 2, h = gid & 3;
    int s = ei[e];
    int d = ei[EE + e];
    const float4* qr = (const float4*)(qpn + (size_t)d*128 + h*32);
    const float4* kr = (const float4*)(kpb + (size_t)s*128 + h*32);
    float acc = 0.f;
    #pragma unroll
    for (int c = 0; c < 8; ++c) {
        float4 a = qr[c], b = kr[c];
        acc += a.x*b.x + a.y*b.y + a.z*b.z + a.w*b.w;
    }
    A[gid] = acc;
}

// ---------- conv (CSR gather): znext[col] += sig_h*rsqrt(din[col]) * sum_e rsdout[row]*v[row]
__global__ __launch_bounds__(256) void k_conv_csr(const int* __restrict__ offsets,
                        const int* __restrict__ csr_row, const int* __restrict__ din,
                        const float* __restrict__ rsd, const float* __restrict__ vbuf,
                        const float* __restrict__ brb, float* __restrict__ znext) {
    int t = threadIdx.x;
    int w = t >> 6, lane = t & 63;
    int col = blockIdx.x*4 + w;
    if (col >= NN) return;
    int s0 = offsets[col], s1 = offsets[col+1];
    if (s0 == s1) return;
    float4 acc = make_float4(0.f, 0.f, 0.f, 0.f);
    for (int j = s0; j < s1; ++j) {
        int row = csr_row[j];
        float rs = rsd[row];
        float4 u = *(const float4*)(vbuf + (size_t)row*256 + lane*4);
        acc.x = fmaf(rs, u.x, acc.x);
        acc.y = fmaf(rs, u.y, acc.y);
        acc.z = fmaf(rs, u.z, acc.z);
        acc.w = fmaf(rs, u.w, acc.w);
    }
    int h = lane >> 4;
    float sig = 1.f / (1.f + __expf(-brb[h]));
    float sc = sig * rsqrtf((float)din[col]);
    float* zp = znext + (size_t)col*256 + lane*4;
    float4 zv = *(float4*)zp;
    zv.x += sc*acc.x; zv.y += sc*acc.y; zv.z += sc*acc.z; zv.w += sc*acc.w;
    *(float4*)zp = zv;
}

// ---------- out[n][o] = sum_f znext[n][f] * Wo[o][f] + Wob[o]
__global__ __launch_bounds__(256) void k_out(const float* __restrict__ znext, const float* __restrict__ WoT,
                      const float* __restrict__ Wob, float* __restrict__ out) {
    int n = blockIdx.x*256 + threadIdx.x;
    if (n >= NN) return;
    float acc[64];
    #pragma unroll
    for (int o = 0; o < 64; ++o) acc[o] = Wob[o];
    const float* zr = znext + (size_t)n*256;
    for (int fc = 0; fc < 64; ++fc) {
        float4 z4 = *(const float4*)(zr + fc*4);
        float zz[4] = {z4.x, z4.y, z4.z, z4.w};
        #pragma unroll
        for (int j = 0; j < 4; ++j) {
            const float* wr = WoT + (fc*4+j)*64;
            #pragma unroll
            for (int o = 0; o < 64; ++o)
                acc[o] = fmaf(zz[j], wr[o], acc[o]);
        }
    }
    float* ob = out + (size_t)n*64;
    #pragma unroll
    for (int o = 0; o < 64; ++o) ob[o] = acc[o];
}

extern "C" void kernel_launch(void* const* d_in, const int* in_sizes, int n_in,
                              void* d_out, int out_size, void* d_ws, size_t ws_size,
                              hipStream_t stream) {
    const float* z    = (const float*)d_in[0];
    const int*   ei   = (const int*)d_in[1];
    const float* Wq   = (const float*)d_in[2];
    const float* Wqb  = (const float*)d_in[3];
    const float* Wk   = (const float*)d_in[4];
    const float* Wkb  = (const float*)d_in[5];
    const float* Wv   = (const float*)d_in[6];
    const float* Wvb  = (const float*)d_in[7];
    const float* Wo   = (const float*)d_in[8];
    const float* Wob  = (const float*)d_in[9];
    const float* brb  = (const float*)d_in[10];
    const float* proj = (const float*)d_in[11];
    const float* g    = (const float*)d_in[12];
    float* out = (float*)d_out;
    float* A   = out + (size_t)NN*64;
    float* ws  = (float*)d_ws;

    float* Wt      = ws;                 // 131072
    float* bext    = ws + 131072;        // 1024
    float* WoT     = ws + 132096;        // 16384
    float* kvs     = ws + 148480;        // 81920
    float* ktg     = ws + 230400;        // 1280
    float* kp_sum  = ws + 231680;        // 128
    unsigned* stab = (unsigned*)(ws + 231808); // 4
    int* din       = (int*)(ws + 231812);      // 50000
    int* dout_     = (int*)(ws + 281812);      // 50000
    float* vbuf    = ws + 331840;        // 12.8M
    float* qp      = ws + 13131840;      // 6.4M
    float* kpb     = ws + 19531840;      // 6.4M
    float* znext   = ws + 25931840;      // 12.8M
    // small scan scratch after znext (~0.6 MB)
    int* offsets   = (int*)(ws + 38731840);    // 50001 (pad to 50004)
    int* cursor    = (int*)(ws + 38781844);    // 50000
    int* bsum      = (int*)(ws + 38831844);    // 196
    int* boff      = (int*)(ws + 38832040);    // 196
    float* rsd     = ws + 38832236;            // 50000 -> end 38882236 floats (~155.5 MB)
    // csr_row (800000 ints) aliases qp, which is dead after k_edge
    int* csr_row   = (int*)qp;

    hipMemsetAsync(ws + 148480, 0, (size_t)(331840 - 148480)*sizeof(float), stream);
    k_prep<<<128, 256, 0, stream>>>(Wq, Wqb, Wk, Wkb, Wv, Wvb, Wo, proj, Wt, bext, WoT);
    k_qkv<<<3125, 256, 0, stream>>>(z, Wt, bext, vbuf, qp, kpb, stab);
    k_deg<<<3125, 256, 0, stream>>>(ei, din, dout_);
    k_rs<<<196, 256, 0, stream>>>(dout_, rsd);
    k_scan_part<<<196, 256, 0, stream>>>(din, bsum);
    k_scan_top<<<1, 64, 0, stream>>>(bsum, boff);
    k_scan_fin<<<196, 256, 0, stream>>>(din, boff, offsets, cursor);
    k_kp<<<512, 256, 0, stream>>>(kpb, stab, kp_sum);
    k_kvs<<<dim3(125, 4), 256, 0, stream>>>(kpb, g, vbuf, kvs, ktg);
    k_znext<<<dim3(196,4), 256, 0, stream>>>(qp, kvs, ktg, kp_sum, znext);
    k_edge<<<12500, 256, 0, stream>>>(ei, qp, kpb, A);
    k_scatter<<<3125, 256, 0, stream>>>(ei, cursor, csr_row);   // csr_row aliases qp (dead now)
    k_conv_csr<<<12500, 256, 0, stream>>>(offsets, csr_row, din, rsd, vbuf, brb, znext);
    k_out<<<196, 256, 0, stream>>>(znext, WoT, Wob, out);
}

// Round 4
// 1152.186 us; speedup vs baseline: 2.2055x; 2.2055x over previous
//
#include <hip/hip_runtime.h>

#define NN 50000
#define EE 800000
#define IND 128
#define NCOL 1024
#define KM 320            // K * Mpad = 10*32
#define M30 30
#define RATIO 0.1825741858f   // 30^-0.5
#define EPSF 1e-6f
#define QKSCALE 0.7071067812f // (1/sqrt(0.25)) * 64^-0.25

__device__ __forceinline__ unsigned f2s(float f) {
    unsigned u = __float_as_uint(f);
    return (u & 0x80000000u) ? ~u : (u | 0x80000000u);
}
__device__ __forceinline__ float s2f(unsigned s) {
    return __uint_as_float((s & 0x80000000u) ? (s & 0x7fffffffu) : ~s);
}

// ---------- prep: Wt[IND][NCOL] (cols: 0-255 s*Wq^T, 256-511 s*Wk^T, 512-767 Wv^T,
// 768-895 Pq[h,m], 896-1023 Pk[h,m]), bias_ext[NCOL], WoT[256][64]
__global__ void k_prep(const float* __restrict__ Wq, const float* __restrict__ Wqb,
                       const float* __restrict__ Wk, const float* __restrict__ Wkb,
                       const float* __restrict__ Wv, const float* __restrict__ Wvb,
                       const float* __restrict__ Wo, const float* __restrict__ proj,
                       float* __restrict__ Wt, float* __restrict__ bext, float* __restrict__ WoT) {
    int i = blockIdx.x;   // 0..127
    int t = threadIdx.x;  // 0..255
    Wt[i*NCOL + t]       = QKSCALE * Wq[t*IND + i];
    Wt[i*NCOL + 256 + t] = QKSCALE * Wk[t*IND + i];
    Wt[i*NCOL + 512 + t] = Wv[t*IND + i];
    {
        const float* W = (t < 128) ? Wq : Wk;
        int c = (t < 128) ? t : (t - 128);
        int h = c >> 5, m = c & 31;
        float val = 0.f;
        if (m < M30) {
            for (int d = 0; d < 64; ++d)
                val += QKSCALE * W[(h*64+d)*IND + i] * proj[m*64 + d];
        }
        Wt[i*NCOL + 768 + t] = val;
    }
    if (t < 128) {
        int f = i*2 + (t >> 6);
        int o = t & 63;
        WoT[f*64 + o] = Wo[o*256 + f];
    }
    if (i == 0) {
        bext[t]       = QKSCALE * Wqb[t];
        bext[256 + t] = QKSCALE * Wkb[t];
        bext[512 + t] = Wvb[t];
        const float* Bb = (t < 128) ? Wqb : Wkb;
        int c = (t < 128) ? t : (t - 128);
        int h = c >> 5, m = c & 31;
        float val = 0.f;
        if (m < M30) {
            for (int d = 0; d < 64; ++d)
                val += QKSCALE * Bb[h*64+d] * proj[m*64 + d];
        }
        bext[768 + t] = val;
    }
}

// ---------- fused QKV + dash GEMM + feature maps. 16 nodes per block.
__global__ __launch_bounds__(256) void k_qkv(const float* __restrict__ z, const float* __restrict__ Wt,
                      const float* __restrict__ bext,
                      float* __restrict__ vbuf, float* __restrict__ qp, float* __restrict__ kpb,
                      unsigned* __restrict__ stab) {
    __shared__ float zl[IND][16];
    __shared__ float diag[16][2][4];
    int t = threadIdx.x;
    int n0 = blockIdx.x * 16;
    #pragma unroll
    for (int ss = 0; ss < 2; ++ss) {
        int s = t + ss*256;
        int node = s >> 5;
        int ii = (s & 31) * 4;
        float4 zv = *(const float4*)(z + (size_t)(n0+node)*IND + ii);
        zl[ii+0][node] = zv.x; zl[ii+1][node] = zv.y; zl[ii+2][node] = zv.z; zl[ii+3][node] = zv.w;
    }
    __syncthreads();
    float aq[16], ak[16], av[16], ad[16];
    {
        float ba = bext[t], bb = bext[256+t], bc = bext[512+t], bd = bext[768+t];
        #pragma unroll
        for (int j = 0; j < 16; ++j) { aq[j]=ba; ak[j]=bb; av[j]=bc; ad[j]=bd; }
    }
    for (int i = 0; i < IND; ++i) {
        float wa = Wt[i*NCOL + t];
        float wb = Wt[i*NCOL + 256 + t];
        float wc = Wt[i*NCOL + 512 + t];
        float wd = Wt[i*NCOL + 768 + t];
        const float4* zr = (const float4*)(&zl[i][0]);
        float zz[16];
        #pragma unroll
        for (int c = 0; c < 4; ++c) {
            float4 zv = zr[c];
            zz[c*4+0]=zv.x; zz[c*4+1]=zv.y; zz[c*4+2]=zv.z; zz[c*4+3]=zv.w;
        }
        #pragma unroll
        for (int j = 0; j < 16; ++j) {
            aq[j] = fmaf(zz[j], wa, aq[j]);
            ak[j] = fmaf(zz[j], wb, ak[j]);
            av[j] = fmaf(zz[j], wc, av[j]);
            ad[j] = fmaf(zz[j], wd, ad[j]);
        }
    }
    int wv_ = t >> 6;
    #pragma unroll
    for (int j = 0; j < 16; ++j) {
        float sq = aq[j]*aq[j];
        float sk = ak[j]*ak[j];
        #pragma unroll
        for (int off = 32; off >= 1; off >>= 1) {
            sq += __shfl_xor(sq, off, 64);
            sk += __shfl_xor(sk, off, 64);
        }
        if ((t & 63) == 0) { diag[j][0][wv_] = 0.5f*sq; diag[j][1][wv_] = 0.5f*sk; }
    }
    #pragma unroll
    for (int j = 0; j < 16; ++j) vbuf[(size_t)(n0+j)*256 + t] = av[j];
    __syncthreads();
    if (t < 128) {
        int h = t >> 5, m = t & 31;
        bool valid = (m < M30);
        #pragma unroll
        for (int j = 0; j < 16; ++j) {
            float dq = ad[j];
            float mx = valid ? dq : -3.0e38f;
            #pragma unroll
            for (int off = 16; off >= 1; off >>= 1)
                mx = fmaxf(mx, __shfl_xor(mx, off, 32));
            float val = 0.f;
            if (valid) val = RATIO * (__expf(dq - diag[j][0][h] - mx) + EPSF);
            qp[(size_t)(n0+j)*128 + t] = val;
        }
    } else {
        int tt = t - 128;
        int h = tt >> 5, m = tt & 31;
        bool valid = (m < M30);
        float bm = -3.0e38f;
        #pragma unroll
        for (int j = 0; j < 16; ++j) {
            float dk = ad[j];
            kpb[(size_t)(n0+j)*128 + tt] = valid ? (dk - diag[j][1][h]) : 0.f;
            if (valid) bm = fmaxf(bm, dk);
        }
        #pragma unroll
        for (int off = 16; off >= 1; off >>= 1)
            bm = fmaxf(bm, __shfl_xor(bm, off, 32));
        if ((tt & 31) == 0) atomicMax(&stab[h], f2s(bm));
    }
}

__global__ void k_deg(const int* __restrict__ ei, int* __restrict__ din, int* __restrict__ dout) {
    int e = blockIdx.x*256 + threadIdx.x;
    if (e < EE) {
        atomicAdd(&dout[ei[e]], 1);
        atomicAdd(&din[ei[EE + e]], 1);
    }
}

// rsdout[n] = dout>0 ? rsqrt(dout) : 0
__global__ void k_rs(const int* __restrict__ dout, float* __restrict__ rsd) {
    int i = blockIdx.x*256 + threadIdx.x;
    if (i < NN) {
        int d = dout[i];
        rsd[i] = d > 0 ? rsqrtf((float)d) : 0.f;
    }
}

// ---------- prefix sum over din (3-kernel scan) ----------
__global__ void k_scan_part(const int* __restrict__ din, int* __restrict__ bsum) {
    __shared__ int red[256];
    int t = threadIdx.x;
    int i = blockIdx.x*256 + t;
    red[t] = (i < NN) ? din[i] : 0;
    __syncthreads();
    for (int off = 128; off >= 1; off >>= 1) {
        if (t < off) red[t] += red[t+off];
        __syncthreads();
    }
    if (t == 0) bsum[blockIdx.x] = red[0];
}
__global__ void k_scan_top(const int* __restrict__ bsum, int* __restrict__ boff) {
    if (threadIdx.x == 0) {
        int acc = 0;
        for (int b = 0; b < 196; ++b) { boff[b] = acc; acc += bsum[b]; }
    }
}
__global__ void k_scan_fin(const int* __restrict__ din, const int* __restrict__ boff,
                           int* __restrict__ offsets, int* __restrict__ cursor) {
    __shared__ int s[256];
    int t = threadIdx.x;
    int i = blockIdx.x*256 + t;
    int v = (i < NN) ? din[i] : 0;
    s[t] = v;
    __syncthreads();
    for (int off = 1; off < 256; off <<= 1) {
        int add = (t >= off) ? s[t-off] : 0;
        __syncthreads();
        s[t] += add;
        __syncthreads();
    }
    int excl = s[t] - v + boff[blockIdx.x];
    if (i < NN) { offsets[i] = excl; cursor[i] = excl; }
    if (i == NN-1) offsets[NN] = excl + v;
}

// scatter edge rows into CSR-by-col order
__global__ void k_scatter(const int* __restrict__ ei, int* __restrict__ cursor,
                          int* __restrict__ csr_row) {
    int e = blockIdx.x*256 + threadIdx.x;
    if (e < EE) {
        int col = ei[EE + e];
        int pos = atomicAdd(&cursor[col], 1);
        csr_row[pos] = ei[e];
    }
}

// ---------- finish kp = ratio*(exp(dash-diag-stab)+eps) in place; accumulate kp_sum[h][m]
__global__ void k_kp(float* __restrict__ kpb, const unsigned* __restrict__ stab,
                     float* __restrict__ kp_sum) {
    __shared__ float red[256];
    int t = threadIdx.x;
    int hm = t & 127;
    int h = hm >> 5, m = hm & 31;
    float st = s2f(stab[h]);
    float ksum = 0.f;
    const int total = NN*128;
    for (int idx = blockIdx.x*256 + t; idx < total; idx += gridDim.x*256) {
        float val = kpb[idx];
        float kpv = 0.f;
        if (m < M30) kpv = RATIO * (__expf(val - st) + EPSF);
        kpb[idx] = kpv;
        ksum += kpv;
    }
    red[t] = ksum;
    __syncthreads();
    if (t < 128) atomicAdd(&kp_sum[hm], red[t] + red[t+128]);
}

// ---------- kvs[h][km][d] = sum_n (kp[n,m]*e^g[n,k]) * v[n,d]; ktg[h][km] = sum_n w
// 500 blocks (125 x 4 heads), 400 nodes/block, 16-node double-buffered tiles.
// Thread (mg=t&15, dg=t>>4): owns m in {2mg,2mg+1}, d in {4dg..4dg+3}, all 10 k.
// NOTE: no min-waves arg — launch_bounds(256,2) forced a 128-VGPR cap and spilled
// the 100-float accumulator to scratch (5.9 GB of HBM traffic, round-3 regression).
__global__ __launch_bounds__(256) void k_kvs(const float* __restrict__ kpb,
                      const float* __restrict__ g, const float* __restrict__ vbuf,
                      float* __restrict__ kvs, float* __restrict__ ktg) {
    __shared__ float kp_l[2][16][32];
    __shared__ float eg_l[2][10][16];
    __shared__ float v_l[2][16][64];
    int t = threadIdx.x;
    int h = blockIdx.y;
    int n0 = blockIdx.x * 400;
    int mg = t & 15, dg = t >> 4;
    int snode = t >> 4, smp = t & 15;
    float acc[2][10][4];
    float wsum[2][10];
    #pragma unroll
    for (int a = 0; a < 2; ++a) {
        #pragma unroll
        for (int k = 0; k < 10; ++k) {
            wsum[a][k] = 0.f;
            #pragma unroll
            for (int b = 0; b < 4; ++b) acc[a][k][b] = 0.f;
        }
    }
    // stage tile 0
    {
        float2 k2 = *(const float2*)(kpb + (size_t)(n0 + snode)*128 + h*32 + smp*2);
        kp_l[0][snode][smp*2] = k2.x; kp_l[0][snode][smp*2+1] = k2.y;
        float4 vv = *(const float4*)(vbuf + (size_t)(n0 + snode)*256 + h*64 + smp*4);
        *(float4*)&v_l[0][snode][smp*4] = vv;
        if (t < 160) {
            int nj = t / 10, kk = t % 10;
            eg_l[0][kk][nj] = __expf(g[(size_t)(n0 + nj)*40 + h*10 + kk]);
        }
    }
    __syncthreads();
    for (int it = 0; it < 25; ++it) {
        int cur = it & 1;
        // issue next-tile global loads into regs (latency hides under compute)
        float2 s_kp = make_float2(0.f, 0.f);
        float4 s_v = make_float4(0.f, 0.f, 0.f, 0.f);
        float s_eg = 0.f;
        if (it + 1 < 25) {
            int nb = n0 + (it+1)*16;
            s_kp = *(const float2*)(kpb + (size_t)(nb + snode)*128 + h*32 + smp*2);
            s_v  = *(const float4*)(vbuf + (size_t)(nb + snode)*256 + h*64 + smp*4);
            if (t < 160) s_eg = g[(size_t)(nb + t/10)*40 + h*10 + (t%10)];
        }
        // compute on current tile, 8 nodes at a time (register-blocked)
        #pragma unroll
        for (int jh = 0; jh < 2; ++jh) {
            float2 kp2[8]; float4 v4[8];
            #pragma unroll
            for (int j = 0; j < 8; ++j) {
                kp2[j] = *(const float2*)&kp_l[cur][jh*8 + j][mg*2];
                v4[j]  = *(const float4*)&v_l[cur][jh*8 + j][dg*4];
            }
            #pragma unroll
            for (int k = 0; k < 10; ++k) {
                float4 ea = *(const float4*)&eg_l[cur][k][jh*8];
                float4 eb = *(const float4*)&eg_l[cur][k][jh*8 + 4];
                float eg8[8] = {ea.x, ea.y, ea.z, ea.w, eb.x, eb.y, eb.z, eb.w};
                #pragma unroll
                for (int j = 0; j < 8; ++j) {
                    float w0 = kp2[j].x * eg8[j];
                    float w1 = kp2[j].y * eg8[j];
                    wsum[0][k] += w0;
                    wsum[1][k] += w1;
                    acc[0][k][0] = fmaf(w0, v4[j].x, acc[0][k][0]);
                    acc[0][k][1] = fmaf(w0, v4[j].y, acc[0][k][1]);
                    acc[0][k][2] = fmaf(w0, v4[j].z, acc[0][k][2]);
                    acc[0][k][3] = fmaf(w0, v4[j].w, acc[0][k][3]);
                    acc[1][k][0] = fmaf(w1, v4[j].x, acc[1][k][0]);
                    acc[1][k][1] = fmaf(w1, v4[j].y, acc[1][k][1]);
                    acc[1][k][2] = fmaf(w1, v4[j].z, acc[1][k][2]);
                    acc[1][k][3] = fmaf(w1, v4[j].w, acc[1][k][3]);
                }
            }
        }
        // write staged tile
        if (it + 1 < 25) {
            int nxt = cur ^ 1;
            kp_l[nxt][snode][smp*2] = s_kp.x; kp_l[nxt][snode][smp*2+1] = s_kp.y;
            *(float4*)&v_l[nxt][snode][smp*4] = s_v;
            if (t < 160) eg_l[nxt][t % 10][t / 10] = __expf(s_eg);
        }
        __syncthreads();
    }
    float* kb = kvs + h*KM*64;
    #pragma unroll
    for (int a = 0; a < 2; ++a)
        #pragma unroll
        for (int k = 0; k < 10; ++k)
            #pragma unroll
            for (int b = 0; b < 4; ++b)
                atomicAdd(&kb[(k*32 + mg*2 + a)*64 + dg*4 + b], acc[a][k][b]);
    if (dg == 0) {
        #pragma unroll
        for (int a = 0; a < 2; ++a)
            #pragma unroll
            for (int k = 0; k < 10; ++k)
                atomicAdd(&ktg[h*KM + k*32 + mg*2 + a], wsum[a][k]);
    }
}

// ---------- per node: norm/qpn (in place), z_den per k, z_next = mean_k(num/den)
__global__ __launch_bounds__(256) void k_znext(float* __restrict__ qp, const float* __restrict__ kvs,
                        const float* __restrict__ ktg, const float* __restrict__ kp_sum,
                        float* __restrict__ znext) {
    int t = threadIdx.x;
    int n = blockIdx.x*256 + t;
    int h = blockIdx.y;
    if (n >= NN) return;
    float q[32];
    float* qb = qp + (size_t)n*128 + h*32;
    #pragma unroll
    for (int c = 0; c < 8; ++c) {
        float4 v4 = *(const float4*)(qb + c*4);
        q[c*4+0]=v4.x; q[c*4+1]=v4.y; q[c*4+2]=v4.z; q[c*4+3]=v4.w;
    }
    const float* ks = kp_sum + h*32;
    float norm = 0.f;
    #pragma unroll
    for (int m = 0; m < 32; ++m) norm = fmaf(q[m], ks[m], norm);
    float rn = 1.f / norm;
    #pragma unroll
    for (int c = 0; c < 8; ++c) {
        float4 v4 = make_float4(q[c*4+0]*rn, q[c*4+1]*rn, q[c*4+2]*rn, q[c*4+3]*rn);
        *(float4*)(qb + c*4) = v4;
    }
    const float* kvh = kvs + h*KM*64;
    const float* kth = ktg + h*KM;
    float* zo = znext + (size_t)n*256 + h*64;
    for (int dc = 0; dc < 4; ++dc) {
        float ms[16];
        #pragma unroll
        for (int d = 0; d < 16; ++d) ms[d] = 0.f;
        for (int k = 0; k < 10; ++k) {
            float den = 0.f;
            #pragma unroll
            for (int m = 0; m < 32; ++m) den = fmaf(q[m], kth[k*32+m], den);
            float rd = 1.f / (den * 10.f);
            const float* base = kvh + k*2048 + dc*16;
            #pragma unroll
            for (int m = 0; m < 32; ++m) {
                float qm = q[m] * rd;
                #pragma unroll
                for (int d = 0; d < 16; ++d)
                    ms[d] = fmaf(qm, base[m*64 + d], ms[d]);
            }
        }
        #pragma unroll
        for (int d = 0; d < 16; ++d) zo[dc*16 + d] = ms[d];
    }
}

// ---------- A[e,h] = dot32(qpn[end], kp[start])
__global__ void k_edge(const int* __restrict__ ei, const float* __restrict__ qpn,
                       const float* __restrict__ kpb, float* __restrict__ A) {
    int gid = blockIdx.x*256 + threadIdx.x;
    int e = gid >> 2, h = gid & 3;
    int s = ei[e];
    int d = ei[EE + e];
    const float4* qr = (const float4*)(qpn + (size_t)d*128 + h*32);
    const float4* kr = (const float4*)(kpb + (size_t)s*128 + h*32);
    float acc = 0.f;
    #pragma unroll
    for (int c = 0; c < 8; ++c) {
        float4 a = qr[c], b = kr[c];
        acc += a.x*b.x + a.y*b.y + a.z*b.z + a.w*b.w;
    }
    A[gid] = acc;
}

// ---------- conv (CSR gather): znext[col] += sig_h*rsqrt(din[col]) * sum_e rsdout[row]*v[row]
__global__ __launch_bounds__(256) void k_conv_csr(const int* __restrict__ offsets,
                        const int* __restrict__ csr_row, const int* __restrict__ din,
                        const float* __restrict__ rsd, const float* __restrict__ vbuf,
                        const float* __restrict__ brb, float* __restrict__ znext) {
    int t = threadIdx.x;
    int w = t >> 6, lane = t & 63;
    int col = blockIdx.x*4 + w;
    if (col >= NN) return;
    int s0 = offsets[col], s1 = offsets[col+1];
    if (s0 == s1) return;
    float4 acc = make_float4(0.f, 0.f, 0.f, 0.f);
    for (int j = s0; j < s1; ++j) {
        int row = csr_row[j];
        float rs = rsd[row];
        float4 u = *(const float4*)(vbuf + (size_t)row*256 + lane*4);
        acc.x = fmaf(rs, u.x, acc.x);
        acc.y = fmaf(rs, u.y, acc.y);
        acc.z = fmaf(rs, u.z, acc.z);
        acc.w = fmaf(rs, u.w, acc.w);
    }
    int h = lane >> 4;
    float sig = 1.f / (1.f + __expf(-brb[h]));
    float sc = sig * rsqrtf((float)din[col]);
    float* zp = znext + (size_t)col*256 + lane*4;
    float4 zv = *(float4*)zp;
    zv.x += sc*acc.x; zv.y += sc*acc.y; zv.z += sc*acc.z; zv.w += sc*acc.w;
    *(float4*)zp = zv;
}

// ---------- out[n][o] = sum_f znext[n][f] * Wo[o][f] + Wob[o]
__global__ __launch_bounds__(256) void k_out(const float* __restrict__ znext, const float* __restrict__ WoT,
                      const float* __restrict__ Wob, float* __restrict__ out) {
    int n = blockIdx.x*256 + threadIdx.x;
    if (n >= NN) return;
    float acc[64];
    #pragma unroll
    for (int o = 0; o < 64; ++o) acc[o] = Wob[o];
    const float* zr = znext + (size_t)n*256;
    for (int fc = 0; fc < 64; ++fc) {
        float4 z4 = *(const float4*)(zr + fc*4);
        float zz[4] = {z4.x, z4.y, z4.z, z4.w};
        #pragma unroll
        for (int j = 0; j < 4; ++j) {
            const float* wr = WoT + (fc*4+j)*64;
            #pragma unroll
            for (int o = 0; o < 64; ++o)
                acc[o] = fmaf(zz[j], wr[o], acc[o]);
        }
    }
    float* ob = out + (size_t)n*64;
    #pragma unroll
    for (int o = 0; o < 64; ++o) ob[o] = acc[o];
}

extern "C" void kernel_launch(void* const* d_in, const int* in_sizes, int n_in,
                              void* d_out, int out_size, void* d_ws, size_t ws_size,
                              hipStream_t stream) {
    const float* z    = (const float*)d_in[0];
    const int*   ei   = (const int*)d_in[1];
    const float* Wq   = (const float*)d_in[2];
    const float* Wqb  = (const float*)d_in[3];
    const float* Wk   = (const float*)d_in[4];
    const float* Wkb  = (const float*)d_in[5];
    const float* Wv   = (const float*)d_in[6];
    const float* Wvb  = (const float*)d_in[7];
    const float* Wo   = (const float*)d_in[8];
    const float* Wob  = (const float*)d_in[9];
    const float* brb  = (const float*)d_in[10];
    const float* proj = (const float*)d_in[11];
    const float* g    = (const float*)d_in[12];
    float* out = (float*)d_out;
    float* A   = out + (size_t)NN*64;
    float* ws  = (float*)d_ws;

    float* Wt      = ws;                 // 131072
    float* bext    = ws + 131072;        // 1024
    float* WoT     = ws + 132096;        // 16384
    float* kvs     = ws + 148480;        // 81920
    float* ktg     = ws + 230400;        // 1280
    float* kp_sum  = ws + 231680;        // 128
    unsigned* stab = (unsigned*)(ws + 231808); // 4
    int* din       = (int*)(ws + 231812);      // 50000
    int* dout_     = (int*)(ws + 281812);      // 50000
    float* vbuf    = ws + 331840;        // 12.8M
    float* qp      = ws + 13131840;      // 6.4M
    float* kpb     = ws + 19531840;      // 6.4M
    float* znext   = ws + 25931840;      // 12.8M
    // small scan scratch after znext (~0.6 MB)
    int* offsets   = (int*)(ws + 38731840);    // 50001 (pad to 50004)
    int* cursor    = (int*)(ws + 38781844);    // 50000
    int* bsum      = (int*)(ws + 38831844);    // 196
    int* boff      = (int*)(ws + 38832040);    // 196
    float* rsd     = ws + 38832236;            // 50000 -> end 38882236 floats (~155.5 MB)
    // csr_row (800000 ints) aliases qp, which is dead after k_edge
    int* csr_row   = (int*)qp;

    hipMemsetAsync(ws + 148480, 0, (size_t)(331840 - 148480)*sizeof(float), stream);
    k_prep<<<128, 256, 0, stream>>>(Wq, Wqb, Wk, Wkb, Wv, Wvb, Wo, proj, Wt, bext, WoT);
    k_qkv<<<3125, 256, 0, stream>>>(z, Wt, bext, vbuf, qp, kpb, stab);
    k_deg<<<3125, 256, 0, stream>>>(ei, din, dout_);
    k_rs<<<196, 256, 0, stream>>>(dout_, rsd);
    k_scan_part<<<196, 256, 0, stream>>>(din, bsum);
    k_scan_top<<<1, 64, 0, stream>>>(bsum, boff);
    k_scan_fin<<<196, 256, 0, stream>>>(din, boff, offsets, cursor);
    k_kp<<<512, 256, 0, stream>>>(kpb, stab, kp_sum);
    k_kvs<<<dim3(125, 4), 256, 0, stream>>>(kpb, g, vbuf, kvs, ktg);
    k_znext<<<dim3(196,4), 256, 0, stream>>>(qp, kvs, ktg, kp_sum, znext);
    k_edge<<<12500, 256, 0, stream>>>(ei, qp, kpb, A);
    k_scatter<<<3125, 256, 0, stream>>>(ei, cursor, csr_row);   // csr_row aliases qp (dead now)
    k_conv_csr<<<12500, 256, 0, stream>>>(offsets, csr_row, din, rsd, vbuf, brb, znext);
    k_out<<<196, 256, 0, stream>>>(znext, WoT, Wob, out);
}

// Round 5
// 1111.207 us; speedup vs baseline: 2.2868x; 1.0369x over previous
//
#include <hip/hip_runtime.h>

#define NN 50000
#define EE 800000
#define IND 128
#define NCOL 1024
#define KM 320            // K * Mpad = 10*32
#define M30 30
#define RATIO 0.1825741858f   // 30^-0.5
#define EPSF 1e-6f
#define QKSCALE 0.7071067812f // (1/sqrt(0.25)) * 64^-0.25

__device__ __forceinline__ unsigned f2s(float f) {
    unsigned u = __float_as_uint(f);
    return (u & 0x80000000u) ? ~u : (u | 0x80000000u);
}
__device__ __forceinline__ float s2f(unsigned s) {
    return __uint_as_float((s & 0x80000000u) ? (s & 0x7fffffffu) : ~s);
}
__device__ __forceinline__ unsigned short f2bf(float f) {   // RTNE fp32->bf16
    unsigned u = __float_as_uint(f);
    unsigned r = u + 0x7fffu + ((u >> 16) & 1u);
    return (unsigned short)(r >> 16);
}
__device__ __forceinline__ float bf2f(unsigned short h) {
    return __uint_as_float(((unsigned)h) << 16);
}

// ---------- prep: Wt[IND][NCOL] (cols: 0-255 s*Wq^T, 256-511 s*Wk^T, 512-767 Wv^T,
// 768-895 Pq[h,m], 896-1023 Pk[h,m]), bias_ext[NCOL], WoT[256][64]
__global__ void k_prep(const float* __restrict__ Wq, const float* __restrict__ Wqb,
                       const float* __restrict__ Wk, const float* __restrict__ Wkb,
                       const float* __restrict__ Wv, const float* __restrict__ Wvb,
                       const float* __restrict__ Wo, const float* __restrict__ proj,
                       float* __restrict__ Wt, float* __restrict__ bext, float* __restrict__ WoT) {
    int i = blockIdx.x;   // 0..127
    int t = threadIdx.x;  // 0..255
    Wt[i*NCOL + t]       = QKSCALE * Wq[t*IND + i];
    Wt[i*NCOL + 256 + t] = QKSCALE * Wk[t*IND + i];
    Wt[i*NCOL + 512 + t] = Wv[t*IND + i];
    {
        const float* W = (t < 128) ? Wq : Wk;
        int c = (t < 128) ? t : (t - 128);
        int h = c >> 5, m = c & 31;
        float val = 0.f;
        if (m < M30) {
            for (int d = 0; d < 64; ++d)
                val += QKSCALE * W[(h*64+d)*IND + i] * proj[m*64 + d];
        }
        Wt[i*NCOL + 768 + t] = val;
    }
    if (t < 128) {
        int f = i*2 + (t >> 6);
        int o = t & 63;
        WoT[f*64 + o] = Wo[o*256 + f];
    }
    if (i == 0) {
        bext[t]       = QKSCALE * Wqb[t];
        bext[256 + t] = QKSCALE * Wkb[t];
        bext[512 + t] = Wvb[t];
        const float* Bb = (t < 128) ? Wqb : Wkb;
        int c = (t < 128) ? t : (t - 128);
        int h = c >> 5, m = c & 31;
        float val = 0.f;
        if (m < M30) {
            for (int d = 0; d < 64; ++d)
                val += QKSCALE * Bb[h*64+d] * proj[m*64 + d];
        }
        bext[768 + t] = val;
    }
}

// ---------- fused QKV + dash GEMM + feature maps. 16 nodes per block.
__global__ __launch_bounds__(256) void k_qkv(const float* __restrict__ z, const float* __restrict__ Wt,
                      const float* __restrict__ bext,
                      float* __restrict__ vbuf, float* __restrict__ qp, float* __restrict__ kpb,
                      unsigned* __restrict__ stab) {
    __shared__ float zl[IND][16];
    __shared__ float diag[16][2][4];
    int t = threadIdx.x;
    int n0 = blockIdx.x * 16;
    #pragma unroll
    for (int ss = 0; ss < 2; ++ss) {
        int s = t + ss*256;
        int node = s >> 5;
        int ii = (s & 31) * 4;
        float4 zv = *(const float4*)(z + (size_t)(n0+node)*IND + ii);
        zl[ii+0][node] = zv.x; zl[ii+1][node] = zv.y; zl[ii+2][node] = zv.z; zl[ii+3][node] = zv.w;
    }
    __syncthreads();
    float aq[16], ak[16], av[16], ad[16];
    {
        float ba = bext[t], bb = bext[256+t], bc = bext[512+t], bd = bext[768+t];
        #pragma unroll
        for (int j = 0; j < 16; ++j) { aq[j]=ba; ak[j]=bb; av[j]=bc; ad[j]=bd; }
    }
    for (int i = 0; i < IND; ++i) {
        float wa = Wt[i*NCOL + t];
        float wb = Wt[i*NCOL + 256 + t];
        float wc = Wt[i*NCOL + 512 + t];
        float wd = Wt[i*NCOL + 768 + t];
        const float4* zr = (const float4*)(&zl[i][0]);
        float zz[16];
        #pragma unroll
        for (int c = 0; c < 4; ++c) {
            float4 zv = zr[c];
            zz[c*4+0]=zv.x; zz[c*4+1]=zv.y; zz[c*4+2]=zv.z; zz[c*4+3]=zv.w;
        }
        #pragma unroll
        for (int j = 0; j < 16; ++j) {
            aq[j] = fmaf(zz[j], wa, aq[j]);
            ak[j] = fmaf(zz[j], wb, ak[j]);
            av[j] = fmaf(zz[j], wc, av[j]);
            ad[j] = fmaf(zz[j], wd, ad[j]);
        }
    }
    int wv_ = t >> 6;
    #pragma unroll
    for (int j = 0; j < 16; ++j) {
        float sq = aq[j]*aq[j];
        float sk = ak[j]*ak[j];
        #pragma unroll
        for (int off = 32; off >= 1; off >>= 1) {
            sq += __shfl_xor(sq, off, 64);
            sk += __shfl_xor(sk, off, 64);
        }
        if ((t & 63) == 0) { diag[j][0][wv_] = 0.5f*sq; diag[j][1][wv_] = 0.5f*sk; }
    }
    #pragma unroll
    for (int j = 0; j < 16; ++j) vbuf[(size_t)(n0+j)*256 + t] = av[j];
    __syncthreads();
    if (t < 128) {
        int h = t >> 5, m = t & 31;
        bool valid = (m < M30);
        #pragma unroll
        for (int j = 0; j < 16; ++j) {
            float dq = ad[j];
            float mx = valid ? dq : -3.0e38f;
            #pragma unroll
            for (int off = 16; off >= 1; off >>= 1)
                mx = fmaxf(mx, __shfl_xor(mx, off, 32));
            float val = 0.f;
            if (valid) val = RATIO * (__expf(dq - diag[j][0][h] - mx) + EPSF);
            qp[(size_t)(n0+j)*128 + t] = val;
        }
    } else {
        int tt = t - 128;
        int h = tt >> 5, m = tt & 31;
        bool valid = (m < M30);
        float bm = -3.0e38f;
        #pragma unroll
        for (int j = 0; j < 16; ++j) {
            float dk = ad[j];
            kpb[(size_t)(n0+j)*128 + tt] = valid ? (dk - diag[j][1][h]) : 0.f;
            if (valid) bm = fmaxf(bm, dk);
        }
        #pragma unroll
        for (int off = 16; off >= 1; off >>= 1)
            bm = fmaxf(bm, __shfl_xor(bm, off, 32));
        if ((tt & 31) == 0) atomicMax(&stab[h], f2s(bm));
    }
}

__global__ void k_deg(const int* __restrict__ ei, int* __restrict__ din, int* __restrict__ dout) {
    int e = blockIdx.x*256 + threadIdx.x;
    if (e < EE) {
        atomicAdd(&dout[ei[e]], 1);
        atomicAdd(&din[ei[EE + e]], 1);
    }
}

// rsdout[n] = dout>0 ? rsqrt(dout) : 0
__global__ void k_rs(const int* __restrict__ dout, float* __restrict__ rsd) {
    int i = blockIdx.x*256 + threadIdx.x;
    if (i < NN) {
        int d = dout[i];
        rsd[i] = d > 0 ? rsqrtf((float)d) : 0.f;
    }
}

// ---------- prefix sum over din (3-kernel scan) ----------
__global__ void k_scan_part(const int* __restrict__ din, int* __restrict__ bsum) {
    __shared__ int red[256];
    int t = threadIdx.x;
    int i = blockIdx.x*256 + t;
    red[t] = (i < NN) ? din[i] : 0;
    __syncthreads();
    for (int off = 128; off >= 1; off >>= 1) {
        if (t < off) red[t] += red[t+off];
        __syncthreads();
    }
    if (t == 0) bsum[blockIdx.x] = red[0];
}
__global__ void k_scan_top(const int* __restrict__ bsum, int* __restrict__ boff) {
    if (threadIdx.x == 0) {
        int acc = 0;
        for (int b = 0; b < 196; ++b) { boff[b] = acc; acc += bsum[b]; }
    }
}
__global__ void k_scan_fin(const int* __restrict__ din, const int* __restrict__ boff,
                           int* __restrict__ offsets, int* __restrict__ cursor) {
    __shared__ int s[256];
    int t = threadIdx.x;
    int i = blockIdx.x*256 + t;
    int v = (i < NN) ? din[i] : 0;
    s[t] = v;
    __syncthreads();
    for (int off = 1; off < 256; off <<= 1) {
        int add = (t >= off) ? s[t-off] : 0;
        __syncthreads();
        s[t] += add;
        __syncthreads();
    }
    int excl = s[t] - v + boff[blockIdx.x];
    if (i < NN) { offsets[i] = excl; cursor[i] = excl; }
    if (i == NN-1) offsets[NN] = excl + v;
}

// scatter edge rows into CSR-by-col order
__global__ void k_scatter(const int* __restrict__ ei, int* __restrict__ cursor,
                          int* __restrict__ csr_row) {
    int e = blockIdx.x*256 + threadIdx.x;
    if (e < EE) {
        int col = ei[EE + e];
        int pos = atomicAdd(&cursor[col], 1);
        csr_row[pos] = ei[e];
    }
}

// ---------- finish kp = ratio*(exp(dash-diag-stab)+eps) in place; accumulate kp_sum[h][m]
__global__ void k_kp(float* __restrict__ kpb, const unsigned* __restrict__ stab,
                     float* __restrict__ kp_sum) {
    __shared__ float red[256];
    int t = threadIdx.x;
    int hm = t & 127;
    int h = hm >> 5, m = hm & 31;
    float st = s2f(stab[h]);
    float ksum = 0.f;
    const int total = NN*128;
    for (int idx = blockIdx.x*256 + t; idx < total; idx += gridDim.x*256) {
        float val = kpb[idx];
        float kpv = 0.f;
        if (m < M30) kpv = RATIO * (__expf(val - st) + EPSF);
        kpb[idx] = kpv;
        ksum += kpv;
    }
    red[t] = ksum;
    __syncthreads();
    if (t < 128) atomicAdd(&kp_sum[hm], red[t] + red[t+128]);
}

// ---------- kvs[h][km][d] = sum_n (kp[n,m]*e^g[n,k]) * v[n,d]; ktg[h][km] = sum_n w
// Split-K: grid (125, 8); by = h*2 + khalf, each block does 5 of 10 gumbel samples.
// 400 nodes/block, 16-node double-buffered tiles.
// Thread (mg=t&15, dg=t>>4): owns m in {2mg,2mg+1}, d in {4dg..4dg+3}, 5 k's.
// NOTE: no min-waves arg in launch_bounds — a 128-VGPR cap spilled the accumulator
// to scratch in round 3 (5.9 GB HBM traffic). Split-K halves acc regs instead.
__global__ __launch_bounds__(256) void k_kvs(const float* __restrict__ kpb,
                      const float* __restrict__ g, const float* __restrict__ vbuf,
                      float* __restrict__ kvs, float* __restrict__ ktg) {
    __shared__ float kp_l[2][16][32];
    __shared__ float eg_l[2][5][16];
    __shared__ float v_l[2][16][64];
    int t = threadIdx.x;
    int by = blockIdx.y;
    int h = by >> 1;
    int k0 = (by & 1) * 5;
    int n0 = blockIdx.x * 400;
    int mg = t & 15, dg = t >> 4;
    int snode = t >> 4, smp = t & 15;
    float acc[2][5][4];
    float wsum[2][5];
    #pragma unroll
    for (int a = 0; a < 2; ++a) {
        #pragma unroll
        for (int k = 0; k < 5; ++k) {
            wsum[a][k] = 0.f;
            #pragma unroll
            for (int b = 0; b < 4; ++b) acc[a][k][b] = 0.f;
        }
    }
    // stage tile 0
    {
        float2 k2 = *(const float2*)(kpb + (size_t)(n0 + snode)*128 + h*32 + smp*2);
        kp_l[0][snode][smp*2] = k2.x; kp_l[0][snode][smp*2+1] = k2.y;
        float4 vv = *(const float4*)(vbuf + (size_t)(n0 + snode)*256 + h*64 + smp*4);
        *(float4*)&v_l[0][snode][smp*4] = vv;
        if (t < 80) {
            int nj = t / 5, kk = t % 5;
            eg_l[0][kk][nj] = __expf(g[(size_t)(n0 + nj)*40 + h*10 + k0 + kk]);
        }
    }
    __syncthreads();
    for (int it = 0; it < 25; ++it) {
        int cur = it & 1;
        // issue next-tile global loads into regs (latency hides under compute)
        float2 s_kp = make_float2(0.f, 0.f);
        float4 s_v = make_float4(0.f, 0.f, 0.f, 0.f);
        float s_eg = 0.f;
        if (it + 1 < 25) {
            int nb = n0 + (it+1)*16;
            s_kp = *(const float2*)(kpb + (size_t)(nb + snode)*128 + h*32 + smp*2);
            s_v  = *(const float4*)(vbuf + (size_t)(nb + snode)*256 + h*64 + smp*4);
            if (t < 80) s_eg = g[(size_t)(nb + t/5)*40 + h*10 + k0 + (t%5)];
        }
        // compute on current tile, 8 nodes at a time (register-blocked)
        #pragma unroll
        for (int jh = 0; jh < 2; ++jh) {
            float2 kp2[8]; float4 v4[8];
            #pragma unroll
            for (int j = 0; j < 8; ++j) {
                kp2[j] = *(const float2*)&kp_l[cur][jh*8 + j][mg*2];
                v4[j]  = *(const float4*)&v_l[cur][jh*8 + j][dg*4];
            }
            #pragma unroll
            for (int k = 0; k < 5; ++k) {
                float4 ea = *(const float4*)&eg_l[cur][k][jh*8];
                float4 eb = *(const float4*)&eg_l[cur][k][jh*8 + 4];
                float eg8[8] = {ea.x, ea.y, ea.z, ea.w, eb.x, eb.y, eb.z, eb.w};
                #pragma unroll
                for (int j = 0; j < 8; ++j) {
                    float w0 = kp2[j].x * eg8[j];
                    float w1 = kp2[j].y * eg8[j];
                    wsum[0][k] += w0;
                    wsum[1][k] += w1;
                    acc[0][k][0] = fmaf(w0, v4[j].x, acc[0][k][0]);
                    acc[0][k][1] = fmaf(w0, v4[j].y, acc[0][k][1]);
                    acc[0][k][2] = fmaf(w0, v4[j].z, acc[0][k][2]);
                    acc[0][k][3] = fmaf(w0, v4[j].w, acc[0][k][3]);
                    acc[1][k][0] = fmaf(w1, v4[j].x, acc[1][k][0]);
                    acc[1][k][1] = fmaf(w1, v4[j].y, acc[1][k][1]);
                    acc[1][k][2] = fmaf(w1, v4[j].z, acc[1][k][2]);
                    acc[1][k][3] = fmaf(w1, v4[j].w, acc[1][k][3]);
                }
            }
        }
        // write staged tile
        if (it + 1 < 25) {
            int nxt = cur ^ 1;
            kp_l[nxt][snode][smp*2] = s_kp.x; kp_l[nxt][snode][smp*2+1] = s_kp.y;
            *(float4*)&v_l[nxt][snode][smp*4] = s_v;
            if (t < 80) eg_l[nxt][t % 5][t / 5] = __expf(s_eg);
        }
        __syncthreads();
    }
    float* kb = kvs + h*KM*64;
    #pragma unroll
    for (int a = 0; a < 2; ++a)
        #pragma unroll
        for (int k = 0; k < 5; ++k)
            #pragma unroll
            for (int b = 0; b < 4; ++b)
                atomicAdd(&kb[((k0+k)*32 + mg*2 + a)*64 + dg*4 + b], acc[a][k][b]);
    if (dg == 0) {
        #pragma unroll
        for (int a = 0; a < 2; ++a)
            #pragma unroll
            for (int k = 0; k < 5; ++k)
                atomicAdd(&ktg[h*KM + (k0+k)*32 + mg*2 + a], wsum[a][k]);
    }
}

// ---------- per node: norm/qpn (in place), z_den per k, z_next = mean_k(num/den)
__global__ __launch_bounds__(256) void k_znext(float* __restrict__ qp, const float* __restrict__ kvs,
                        const float* __restrict__ ktg, const float* __restrict__ kp_sum,
                        float* __restrict__ znext) {
    int t = threadIdx.x;
    int n = blockIdx.x*256 + t;
    int h = blockIdx.y;
    if (n >= NN) return;
    float q[32];
    float* qb = qp + (size_t)n*128 + h*32;
    #pragma unroll
    for (int c = 0; c < 8; ++c) {
        float4 v4 = *(const float4*)(qb + c*4);
        q[c*4+0]=v4.x; q[c*4+1]=v4.y; q[c*4+2]=v4.z; q[c*4+3]=v4.w;
    }
    const float* ks = kp_sum + h*32;
    float norm = 0.f;
    #pragma unroll
    for (int m = 0; m < 32; ++m) norm = fmaf(q[m], ks[m], norm);
    float rn = 1.f / norm;
    #pragma unroll
    for (int c = 0; c < 8; ++c) {
        float4 v4 = make_float4(q[c*4+0]*rn, q[c*4+1]*rn, q[c*4+2]*rn, q[c*4+3]*rn);
        *(float4*)(qb + c*4) = v4;
    }
    const float* kvh = kvs + h*KM*64;
    const float* kth = ktg + h*KM;
    float* zo = znext + (size_t)n*256 + h*64;
    for (int dc = 0; dc < 4; ++dc) {
        float ms[16];
        #pragma unroll
        for (int d = 0; d < 16; ++d) ms[d] = 0.f;
        for (int k = 0; k < 10; ++k) {
            float den = 0.f;
            #pragma unroll
            for (int m = 0; m < 32; ++m) den = fmaf(q[m], kth[k*32+m], den);
            float rd = 1.f / (den * 10.f);
            const float* base = kvh + k*2048 + dc*16;
            #pragma unroll
            for (int m = 0; m < 32; ++m) {
                float qm = q[m] * rd;
                #pragma unroll
                for (int d = 0; d < 16; ++d)
                    ms[d] = fmaf(qm, base[m*64 + d], ms[d]);
            }
        }
        #pragma unroll
        for (int d = 0; d < 16; ++d) zo[dc*16 + d] = ms[d];
    }
}

// ---------- A[e,h] = dot32(qpn[end], kp[start])
__global__ void k_edge(const int* __restrict__ ei, const float* __restrict__ qpn,
                       const float* __restrict__ kpb, float* __restrict__ A) {
    int gid = blockIdx.x*256 + threadIdx.x;
    int e = gid >> 2, h = gid & 3;
    int s = ei[e];
    int d = ei[EE + e];
    const float4* qr = (const float4*)(qpn + (size_t)d*128 + h*32);
    const float4* kr = (const float4*)(kpb + (size_t)s*128 + h*32);
    float acc = 0.f;
    #pragma unroll
    for (int c = 0; c < 8; ++c) {
        float4 a = qr[c], b = kr[c];
        acc += a.x*b.x + a.y*b.y + a.z*b.z + a.w*b.w;
    }
    A[gid] = acc;
}

// ---------- vr[row] = rsd[row] * v[row], bf16-compressed (halves conv gather traffic)
__global__ __launch_bounds__(256) void k_vr(const float* __restrict__ vbuf,
                      const float* __restrict__ rsd, unsigned short* __restrict__ vr) {
    int t = threadIdx.x;
    int row = blockIdx.x*4 + (t >> 6);
    int lane = t & 63;
    float rs = rsd[row];
    float4 v4 = *(const float4*)(vbuf + (size_t)row*256 + lane*4);
    ushort4 o;
    o.x = f2bf(rs * v4.x);
    o.y = f2bf(rs * v4.y);
    o.z = f2bf(rs * v4.z);
    o.w = f2bf(rs * v4.w);
    *(ushort4*)(vr + (size_t)row*256 + lane*4) = o;
}

// ---------- conv (CSR gather, bf16): znext[col] += sig_h*rsqrt(din[col]) * sum_e vr[row]
__global__ __launch_bounds__(256) void k_conv_csr(const int* __restrict__ offsets,
                        const int* __restrict__ csr_row, const int* __restrict__ din,
                        const unsigned short* __restrict__ vr,
                        const float* __restrict__ brb, float* __restrict__ znext) {
    int t = threadIdx.x;
    int w = t >> 6, lane = t & 63;
    int col = blockIdx.x*4 + w;
    if (col >= NN) return;
    int s0 = offsets[col], s1 = offsets[col+1];
    if (s0 == s1) return;
    float a0 = 0.f, a1 = 0.f, a2 = 0.f, a3 = 0.f;
    for (int j = s0; j < s1; ++j) {
        int row = csr_row[j];
        ushort4 u = *(const ushort4*)(vr + (size_t)row*256 + lane*4);
        a0 += bf2f(u.x);
        a1 += bf2f(u.y);
        a2 += bf2f(u.z);
        a3 += bf2f(u.w);
    }
    int h = lane >> 4;
    float sig = 1.f / (1.f + __expf(-brb[h]));
    float sc = sig * rsqrtf((float)din[col]);
    float* zp = znext + (size_t)col*256 + lane*4;
    float4 zv = *(float4*)zp;
    zv.x += sc*a0; zv.y += sc*a1; zv.z += sc*a2; zv.w += sc*a3;
    *(float4*)zp = zv;
}

// ---------- out[n][o] = sum_f znext[n][f] * Wo[o][f] + Wob[o]
__global__ __launch_bounds__(256) void k_out(const float* __restrict__ znext, const float* __restrict__ WoT,
                      const float* __restrict__ Wob, float* __restrict__ out) {
    int n = blockIdx.x*256 + threadIdx.x;
    if (n >= NN) return;
    float acc[64];
    #pragma unroll
    for (int o = 0; o < 64; ++o) acc[o] = Wob[o];
    const float* zr = znext + (size_t)n*256;
    for (int fc = 0; fc < 64; ++fc) {
        float4 z4 = *(const float4*)(zr + fc*4);
        float zz[4] = {z4.x, z4.y, z4.z, z4.w};
        #pragma unroll
        for (int j = 0; j < 4; ++j) {
            const float* wr = WoT + (fc*4+j)*64;
            #pragma unroll
            for (int o = 0; o < 64; ++o)
                acc[o] = fmaf(zz[j], wr[o], acc[o]);
        }
    }
    float* ob = out + (size_t)n*64;
    #pragma unroll
    for (int o = 0; o < 64; ++o) ob[o] = acc[o];
}

extern "C" void kernel_launch(void* const* d_in, const int* in_sizes, int n_in,
                              void* d_out, int out_size, void* d_ws, size_t ws_size,
                              hipStream_t stream) {
    const float* z    = (const float*)d_in[0];
    const int*   ei   = (const int*)d_in[1];
    const float* Wq   = (const float*)d_in[2];
    const float* Wqb  = (const float*)d_in[3];
    const float* Wk   = (const float*)d_in[4];
    const float* Wkb  = (const float*)d_in[5];
    const float* Wv   = (const float*)d_in[6];
    const float* Wvb  = (const float*)d_in[7];
    const float* Wo   = (const float*)d_in[8];
    const float* Wob  = (const float*)d_in[9];
    const float* brb  = (const float*)d_in[10];
    const float* proj = (const float*)d_in[11];
    const float* g    = (const float*)d_in[12];
    float* out = (float*)d_out;
    float* A   = out + (size_t)NN*64;
    float* ws  = (float*)d_ws;

    float* Wt      = ws;                 // 131072
    float* bext    = ws + 131072;        // 1024
    float* WoT     = ws + 132096;        // 16384
    float* kvs     = ws + 148480;        // 81920
    float* ktg     = ws + 230400;        // 1280
    float* kp_sum  = ws + 231680;        // 128
    unsigned* stab = (unsigned*)(ws + 231808); // 4
    int* din       = (int*)(ws + 231812);      // 50000
    int* dout_     = (int*)(ws + 281812);      // 50000
    float* vbuf    = ws + 331840;        // 12.8M
    float* qp      = ws + 13131840;      // 6.4M
    float* kpb     = ws + 19531840;      // 6.4M
    float* znext   = ws + 25931840;      // 12.8M
    // small scan scratch after znext (~0.6 MB)
    int* offsets   = (int*)(ws + 38731840);    // 50001 (pad to 50004)
    int* cursor    = (int*)(ws + 38781844);    // 50000
    int* bsum      = (int*)(ws + 38831844);    // 196
    int* boff      = (int*)(ws + 38832040);    // 196
    float* rsd     = ws + 38832236;            // 50000 -> end 38882236 floats (~155.5 MB)
    // aliases: csr_row (800000 ints) -> kpb (dead after k_edge);
    //          vr (12.8M ushorts = 6.4M float-slots) -> qp (dead after k_edge)
    int* csr_row        = (int*)kpb;
    unsigned short* vr  = (unsigned short*)qp;

    hipMemsetAsync(ws + 148480, 0, (size_t)(331840 - 148480)*sizeof(float), stream);
    k_prep<<<128, 256, 0, stream>>>(Wq, Wqb, Wk, Wkb, Wv, Wvb, Wo, proj, Wt, bext, WoT);
    k_qkv<<<3125, 256, 0, stream>>>(z, Wt, bext, vbuf, qp, kpb, stab);
    k_deg<<<3125, 256, 0, stream>>>(ei, din, dout_);
    k_rs<<<196, 256, 0, stream>>>(dout_, rsd);
    k_scan_part<<<196, 256, 0, stream>>>(din, bsum);
    k_scan_top<<<1, 64, 0, stream>>>(bsum, boff);
    k_scan_fin<<<196, 256, 0, stream>>>(din, boff, offsets, cursor);
    k_kp<<<512, 256, 0, stream>>>(kpb, stab, kp_sum);
    k_kvs<<<dim3(125, 8), 256, 0, stream>>>(kpb, g, vbuf, kvs, ktg);
    k_znext<<<dim3(196,4), 256, 0, stream>>>(qp, kvs, ktg, kp_sum, znext);
    k_edge<<<12500, 256, 0, stream>>>(ei, qp, kpb, A);
    k_scatter<<<3125, 256, 0, stream>>>(ei, cursor, csr_row);       // csr_row aliases kpb (dead now)
    k_vr<<<12500, 256, 0, stream>>>(vbuf, rsd, vr);                 // vr aliases qp (dead now)
    k_conv_csr<<<12500, 256, 0, stream>>>(offsets, csr_row, din, vr, brb, znext);
    k_out<<<196, 256, 0, stream>>>(znext, WoT, Wob, out);
}

// Round 7
// 938.936 us; speedup vs baseline: 2.7064x; 1.1835x over previous
//
#include <hip/hip_runtime.h>

#define NN 50000
#define EE 800000
#define IND 128
#define NCOL 1024
#define KM 320            // K * Mpad = 10*32
#define M30 30
#define RATIO 0.1825741858f   // 30^-0.5
#define EPSF 1e-6f
#define QKSCALE 0.7071067812f // (1/sqrt(0.25)) * 64^-0.25
#define VTS 50176             // vT row stride (196*256)
#define KVSNB 196             // k_kvs node-chunk blocks (256 nodes each)

typedef __attribute__((ext_vector_type(8))) short bf16x8;
typedef __attribute__((ext_vector_type(4))) float f32x4;

__device__ __forceinline__ unsigned f2s(float f) {
    unsigned u = __float_as_uint(f);
    return (u & 0x80000000u) ? ~u : (u | 0x80000000u);
}
__device__ __forceinline__ float s2f(unsigned s) {
    return __uint_as_float((s & 0x80000000u) ? (s & 0x7fffffffu) : ~s);
}
__device__ __forceinline__ unsigned short f2bf(float f) {   // RTNE fp32->bf16
    unsigned u = __float_as_uint(f);
    unsigned r = u + 0x7fffu + ((u >> 16) & 1u);
    return (unsigned short)(r >> 16);
}
__device__ __forceinline__ float bf2f(unsigned short h) {
    return __uint_as_float(((unsigned)h) << 16);
}

// ---------- prep: Wt[IND][NCOL] (cols: 0-255 s*Wq^T, 256-511 s*Wk^T, 512-767 Wv^T,
// 768-895 Pq[h,m], 896-1023 Pk[h,m]), bias_ext[NCOL], WoT[256][64]
__global__ void k_prep(const float* __restrict__ Wq, const float* __restrict__ Wqb,
                       const float* __restrict__ Wk, const float* __restrict__ Wkb,
                       const float* __restrict__ Wv, const float* __restrict__ Wvb,
                       const float* __restrict__ Wo, const float* __restrict__ proj,
                       float* __restrict__ Wt, float* __restrict__ bext, float* __restrict__ WoT) {
    int i = blockIdx.x;   // 0..127
    int t = threadIdx.x;  // 0..255
    Wt[i*NCOL + t]       = QKSCALE * Wq[t*IND + i];
    Wt[i*NCOL + 256 + t] = QKSCALE * Wk[t*IND + i];
    Wt[i*NCOL + 512 + t] = Wv[t*IND + i];
    {
        const float* W = (t < 128) ? Wq : Wk;
        int c = (t < 128) ? t : (t - 128);
        int h = c >> 5, m = c & 31;
        float val = 0.f;
        if (m < M30) {
            for (int d = 0; d < 64; ++d)
                val += QKSCALE * W[(h*64+d)*IND + i] * proj[m*64 + d];
        }
        Wt[i*NCOL + 768 + t] = val;
    }
    if (t < 128) {
        int f = i*2 + (t >> 6);
        int o = t & 63;
        WoT[f*64 + o] = Wo[o*256 + f];
    }
    if (i == 0) {
        bext[t]       = QKSCALE * Wqb[t];
        bext[256 + t] = QKSCALE * Wkb[t];
        bext[512 + t] = Wvb[t];
        const float* Bb = (t < 128) ? Wqb : Wkb;
        int c = (t < 128) ? t : (t - 128);
        int h = c >> 5, m = c & 31;
        float val = 0.f;
        if (m < M30) {
            for (int d = 0; d < 64; ++d)
                val += QKSCALE * Bb[h*64+d] * proj[m*64 + d];
        }
        bext[768 + t] = val;
    }
}

// ---------- zero the never-written tail cols [50000,50176) of all 256 vT rows.
// vT aliases znext: without this, graph replays read the previous call's znext
// bytes as bf16 (possible Inf/NaN) and MFMA's 0*Inf=NaN diverges the output.
__global__ void k_ztail(unsigned* __restrict__ vT32) {
    int idx = blockIdx.x*256 + threadIdx.x;  // 88 blocks * 256 = 22528 = 256*88
    int row = idx / 88, c = idx - row*88;
    vT32[(size_t)row * (VTS/2) + (50000/2) + c] = 0u;
}

// ---------- fused QKV + dash GEMM + feature maps. 16 nodes per block.
// Also emits vT[h*64+d][n] bf16 (transposed V) for the MFMA kvs kernel.
__global__ __launch_bounds__(256) void k_qkv(const float* __restrict__ z, const float* __restrict__ Wt,
                      const float* __restrict__ bext,
                      float* __restrict__ vbuf, float* __restrict__ qp, float* __restrict__ kpb,
                      unsigned* __restrict__ stab, unsigned short* __restrict__ vT) {
    __shared__ float zl[IND][16];
    __shared__ float diag[16][2][4];
    int t = threadIdx.x;
    int n0 = blockIdx.x * 16;
    #pragma unroll
    for (int ss = 0; ss < 2; ++ss) {
        int s = t + ss*256;
        int node = s >> 5;
        int ii = (s & 31) * 4;
        float4 zv = *(const float4*)(z + (size_t)(n0+node)*IND + ii);
        zl[ii+0][node] = zv.x; zl[ii+1][node] = zv.y; zl[ii+2][node] = zv.z; zl[ii+3][node] = zv.w;
    }
    __syncthreads();
    float aq[16], ak[16], av[16], ad[16];
    {
        float ba = bext[t], bb = bext[256+t], bc = bext[512+t], bd = bext[768+t];
        #pragma unroll
        for (int j = 0; j < 16; ++j) { aq[j]=ba; ak[j]=bb; av[j]=bc; ad[j]=bd; }
    }
    for (int i = 0; i < IND; ++i) {
        float wa = Wt[i*NCOL + t];
        float wb = Wt[i*NCOL + 256 + t];
        float wc = Wt[i*NCOL + 512 + t];
        float wd = Wt[i*NCOL + 768 + t];
        const float4* zr = (const float4*)(&zl[i][0]);
        float zz[16];
        #pragma unroll
        for (int c = 0; c < 4; ++c) {
            float4 zv = zr[c];
            zz[c*4+0]=zv.x; zz[c*4+1]=zv.y; zz[c*4+2]=zv.z; zz[c*4+3]=zv.w;
        }
        #pragma unroll
        for (int j = 0; j < 16; ++j) {
            aq[j] = fmaf(zz[j], wa, aq[j]);
            ak[j] = fmaf(zz[j], wb, ak[j]);
            av[j] = fmaf(zz[j], wc, av[j]);
            ad[j] = fmaf(zz[j], wd, ad[j]);
        }
    }
    int wv_ = t >> 6;
    #pragma unroll
    for (int j = 0; j < 16; ++j) {
        float sq = aq[j]*aq[j];
        float sk = ak[j]*ak[j];
        #pragma unroll
        for (int off = 32; off >= 1; off >>= 1) {
            sq += __shfl_xor(sq, off, 64);
            sk += __shfl_xor(sk, off, 64);
        }
        if ((t & 63) == 0) { diag[j][0][wv_] = 0.5f*sq; diag[j][1][wv_] = 0.5f*sk; }
    }
    #pragma unroll
    for (int j = 0; j < 16; ++j) vbuf[(size_t)(n0+j)*256 + t] = av[j];
    // transposed bf16 V: row t = h*64+d, cols n0..n0+15
    {
        unsigned short* vr = vT + (size_t)t * VTS + n0;
        unsigned dwv[8];
        #pragma unroll
        for (int c = 0; c < 8; ++c)
            dwv[c] = (unsigned)f2bf(av[c*2]) | ((unsigned)f2bf(av[c*2+1]) << 16);
        *(uint4*)(vr)     = make_uint4(dwv[0], dwv[1], dwv[2], dwv[3]);
        *(uint4*)(vr + 8) = make_uint4(dwv[4], dwv[5], dwv[6], dwv[7]);
    }
    __syncthreads();
    if (t < 128) {
        int h = t >> 5, m = t & 31;
        bool valid = (m < M30);
        #pragma unroll
        for (int j = 0; j < 16; ++j) {
            float dq = ad[j];
            float mx = valid ? dq : -3.0e38f;
            #pragma unroll
            for (int off = 16; off >= 1; off >>= 1)
                mx = fmaxf(mx, __shfl_xor(mx, off, 32));
            float val = 0.f;
            if (valid) val = RATIO * (__expf(dq - diag[j][0][h] - mx) + EPSF);
            qp[(size_t)(n0+j)*128 + t] = val;
        }
    } else {
        int tt = t - 128;
        int h = tt >> 5, m = tt & 31;
        bool valid = (m < M30);
        float bm = -3.0e38f;
        #pragma unroll
        for (int j = 0; j < 16; ++j) {
            float dk = ad[j];
            kpb[(size_t)(n0+j)*128 + tt] = valid ? (dk - diag[j][1][h]) : 0.f;
            if (valid) bm = fmaxf(bm, dk);
        }
        #pragma unroll
        for (int off = 16; off >= 1; off >>= 1)
            bm = fmaxf(bm, __shfl_xor(bm, off, 32));
        if ((tt & 31) == 0) atomicMax(&stab[h], f2s(bm));
    }
}

__global__ void k_deg(const int* __restrict__ ei, int* __restrict__ din, int* __restrict__ dout) {
    int e = blockIdx.x*256 + threadIdx.x;
    if (e < EE) {
        atomicAdd(&dout[ei[e]], 1);
        atomicAdd(&din[ei[EE + e]], 1);
    }
}

// rsdout[n] = dout>0 ? rsqrt(dout) : 0
__global__ void k_rs(const int* __restrict__ dout, float* __restrict__ rsd) {
    int i = blockIdx.x*256 + threadIdx.x;
    if (i < NN) {
        int d = dout[i];
        rsd[i] = d > 0 ? rsqrtf((float)d) : 0.f;
    }
}

// ---------- prefix sum over din (3-kernel scan) ----------
__global__ void k_scan_part(const int* __restrict__ din, int* __restrict__ bsum) {
    __shared__ int red[256];
    int t = threadIdx.x;
    int i = blockIdx.x*256 + t;
    red[t] = (i < NN) ? din[i] : 0;
    __syncthreads();
    for (int off = 128; off >= 1; off >>= 1) {
        if (t < off) red[t] += red[t+off];
        __syncthreads();
    }
    if (t == 0) bsum[blockIdx.x] = red[0];
}
__global__ void k_scan_top(const int* __restrict__ bsum, int* __restrict__ boff) {
    if (threadIdx.x == 0) {
        int acc = 0;
        for (int b = 0; b < 196; ++b) { boff[b] = acc; acc += bsum[b]; }
    }
}
__global__ void k_scan_fin(const int* __restrict__ din, const int* __restrict__ boff,
                           int* __restrict__ offsets, int* __restrict__ cursor) {
    __shared__ int s[256];
    int t = threadIdx.x;
    int i = blockIdx.x*256 + t;
    int v = (i < NN) ? din[i] : 0;
    s[t] = v;
    __syncthreads();
    for (int off = 1; off < 256; off <<= 1) {
        int add = (t >= off) ? s[t-off] : 0;
        __syncthreads();
        s[t] += add;
        __syncthreads();
    }
    int excl = s[t] - v + boff[blockIdx.x];
    if (i < NN) { offsets[i] = excl; cursor[i] = excl; }
    if (i == NN-1) offsets[NN] = excl + v;
}

// scatter edge rows into CSR-by-col order
__global__ void k_scatter(const int* __restrict__ ei, int* __restrict__ cursor,
                          int* __restrict__ csr_row) {
    int e = blockIdx.x*256 + threadIdx.x;
    if (e < EE) {
        int col = ei[EE + e];
        int pos = atomicAdd(&cursor[col], 1);
        csr_row[pos] = ei[e];
    }
}

// ---------- finish kp = ratio*(exp(dash-diag-stab)+eps) in place; accumulate kp_sum[h][m]
__global__ void k_kp(float* __restrict__ kpb, const unsigned* __restrict__ stab,
                     float* __restrict__ kp_sum) {
    __shared__ float red[256];
    int t = threadIdx.x;
    int hm = t & 127;
    int h = hm >> 5, m = hm & 31;
    float st = s2f(stab[h]);
    float ksum = 0.f;
    const int total = NN*128;
    for (int idx = blockIdx.x*256 + t; idx < total; idx += gridDim.x*256) {
        float val = kpb[idx];
        float kpv = 0.f;
        if (m < M30) kpv = RATIO * (__expf(val - st) + EPSF);
        kpb[idx] = kpv;
        ksum += kpv;
    }
    red[t] = ksum;
    __syncthreads();
    if (t < 128) atomicAdd(&kp_sum[hm], red[t] + red[t+128]);
}

// ---------- kvs[h][km][d] = sum_n w[n,km]*v[n,d] via MFMA (16x16x32 bf16).
// Grid (KVSNB, 4 heads); block = 256 nodes, 8 steps of 32 nodes.
// 4 waves; wave w owns km rows [80w, 80w+80) = 5 tiles of 16; d = 4 tiles of 16.
// w[km][n] built per-thread (row km = t, + t+256 for t<64) in bf16 (truncation;
// wsum accumulated from the ROUNDED values so num/den bias cancels in the ratio).
// kp read per-lane from global (lanes span m -> coalesced 128B, L2-hot).
__global__ __launch_bounds__(256) void k_kvs(const float* __restrict__ kpb,
                      const float* __restrict__ g, const unsigned short* __restrict__ vT,
                      float* __restrict__ kvs, float* __restrict__ ktg) {
    __shared__ __align__(16) unsigned short w_l[320*40]; // row stride 40 bf16 (80B)
    __shared__ __align__(16) unsigned short v_l[64*40];
    __shared__ __align__(16) float eg_l[10][36];
    int t = threadIdx.x;
    int h = blockIdx.y;
    int n0b = blockIdx.x * 256;
    int lane = t & 63;
    int wb = (t >> 6) * 80;            // wave's km base
    int arow = lane & 15;
    int acol = (lane >> 4) * 8;        // bf16 col offset of the 8-elem fragment
    f32x4 acc[5][4];
    #pragma unroll
    for (int kt = 0; kt < 5; ++kt)
        #pragma unroll
        for (int dt = 0; dt < 4; ++dt)
            acc[kt][dt] = (f32x4){0.f, 0.f, 0.f, 0.f};
    float wsum0 = 0.f, wsum1 = 0.f;
    int k0 = t >> 5, m0 = t & 31;      // row t = k0*32 + m0
    int k1 = 8 + (t >> 5), m1 = t & 31; // row t+256 (t<64)

    for (int st = 0; st < 8; ++st) {
        int n0 = n0b + st * 32;
        __syncthreads();               // prev tile consumed by MFMA
        // ---- stage eg[k][n] (fp32, broadcast-read layout)
        #pragma unroll
        for (int i = 0; i < 2; ++i) {
            int flat = t + i*256;
            if (flat < 320) {
                int kk = flat % 10, n = flat / 10;
                float e = 0.f;
                if (n0 + n < NN) e = __expf(g[(size_t)(n0+n)*40 + h*10 + kk]);
                eg_l[kk][n] = e;
            }
        }
        // ---- stage v tile (bf16 direct from vT; tail cols are zeroed by k_ztail)
        {
            int d = t >> 2, seg = t & 3;
            uint4 vv = *(const uint4*)(vT + (size_t)(h*64 + d)*VTS + n0 + seg*8);
            *(uint4*)(&v_l[d*40 + seg*8]) = vv;
        }
        __syncthreads();
        // ---- build w rows (bf16) + wsum from rounded values
        {
            const float* kprow = kpb + (size_t)n0*128 + h*32;
            bool full = (n0 + 32 <= NN);
            // row t
            {
                unsigned dw[16];
                float s = 0.f;
                #pragma unroll
                for (int c = 0; c < 16; ++c) {
                    int na = c*2, nb = c*2 + 1;
                    float kpa = 0.f, kpc = 0.f;
                    if (full) {
                        kpa = kprow[(size_t)na*128 + m0];
                        kpc = kprow[(size_t)nb*128 + m0];
                    } else {
                        if (n0 + na < NN) kpa = kprow[(size_t)na*128 + m0];
                        if (n0 + nb < NN) kpc = kprow[(size_t)nb*128 + m0];
                    }
                    unsigned ua = __float_as_uint(kpa * eg_l[k0][na]);
                    unsigned ub = __float_as_uint(kpc * eg_l[k0][nb]);
                    s += __uint_as_float(ua & 0xFFFF0000u) + __uint_as_float(ub & 0xFFFF0000u);
                    dw[c] = (ua >> 16) | (ub & 0xFFFF0000u);
                }
                wsum0 += s;
                uint4* wp = (uint4*)(&w_l[t*40]);
                wp[0] = make_uint4(dw[0], dw[1], dw[2],  dw[3]);
                wp[1] = make_uint4(dw[4], dw[5], dw[6],  dw[7]);
                wp[2] = make_uint4(dw[8], dw[9], dw[10], dw[11]);
                wp[3] = make_uint4(dw[12],dw[13],dw[14], dw[15]);
            }
            // row t+256
            if (t < 64) {
                unsigned dw[16];
                float s = 0.f;
                #pragma unroll
                for (int c = 0; c < 16; ++c) {
                    int na = c*2, nb = c*2 + 1;
                    float kpa = 0.f, kpc = 0.f;
                    if (full) {
                        kpa = kprow[(size_t)na*128 + m1];
                        kpc = kprow[(size_t)nb*128 + m1];
                    } else {
                        if (n0 + na < NN) kpa = kprow[(size_t)na*128 + m1];
                        if (n0 + nb < NN) kpc = kprow[(size_t)nb*128 + m1];
                    }
                    unsigned ua = __float_as_uint(kpa * eg_l[k1][na]);
                    unsigned ub = __float_as_uint(kpc * eg_l[k1][nb]);
                    s += __uint_as_float(ua & 0xFFFF0000u) + __uint_as_float(ub & 0xFFFF0000u);
                    dw[c] = (ua >> 16) | (ub & 0xFFFF0000u);
                }
                wsum1 += s;
                uint4* wp = (uint4*)(&w_l[(t + 256)*40]);
                wp[0] = make_uint4(dw[0], dw[1], dw[2],  dw[3]);
                wp[1] = make_uint4(dw[4], dw[5], dw[6],  dw[7]);
                wp[2] = make_uint4(dw[8], dw[9], dw[10], dw[11]);
                wp[3] = make_uint4(dw[12],dw[13],dw[14], dw[15]);
            }
        }
        __syncthreads();
        // ---- MFMA: 4 B-frags shared across 5 A-tiles
        bf16x8 Bf[4];
        #pragma unroll
        for (int dt = 0; dt < 4; ++dt)
            Bf[dt] = *(const bf16x8*)(&v_l[(dt*16 + arow)*40 + acol]);
        #pragma unroll
        for (int kt = 0; kt < 5; ++kt) {
            bf16x8 Af = *(const bf16x8*)(&w_l[(wb + kt*16 + arow)*40 + acol]);
            #pragma unroll
            for (int dt = 0; dt < 4; ++dt)
                acc[kt][dt] = __builtin_amdgcn_mfma_f32_16x16x32_bf16(Af, Bf[dt], acc[kt][dt], 0, 0, 0);
        }
    }
    // ---- epilogue: D lane mapping col=lane&15, row=(lane>>4)*4+reg
    {
        int orow = (lane >> 4) * 4;
        int ocol = lane & 15;
        float* kb = kvs + h*KM*64;
        #pragma unroll
        for (int kt = 0; kt < 5; ++kt)
            #pragma unroll
            for (int dt = 0; dt < 4; ++dt)
                #pragma unroll
                for (int r = 0; r < 4; ++r)
                    atomicAdd(&kb[(wb + kt*16 + orow + r)*64 + dt*16 + ocol], acc[kt][dt][r]);
        atomicAdd(&ktg[h*KM + t], wsum0);
        if (t < 64) atomicAdd(&ktg[h*KM + 256 + t], wsum1);
    }
}

// ---------- per node: norm/qpn (in place), z_den per k, z_next = mean_k(num/den)
__global__ __launch_bounds__(256) void k_znext(float* __restrict__ qp, const float* __restrict__ kvs,
                        const float* __restrict__ ktg, const float* __restrict__ kp_sum,
                        float* __restrict__ znext) {
    int t = threadIdx.x;
    int n = blockIdx.x*256 + t;
    int h = blockIdx.y;
    if (n >= NN) return;
    float q[32];
    float* qb = qp + (size_t)n*128 + h*32;
    #pragma unroll
    for (int c = 0; c < 8; ++c) {
        float4 v4 = *(const float4*)(qb + c*4);
        q[c*4+0]=v4.x; q[c*4+1]=v4.y; q[c*4+2]=v4.z; q[c*4+3]=v4.w;
    }
    const float* ks = kp_sum + h*32;
    float norm = 0.f;
    #pragma unroll
    for (int m = 0; m < 32; ++m) norm = fmaf(q[m], ks[m], norm);
    float rn = 1.f / norm;
    #pragma unroll
    for (int c = 0; c < 8; ++c) {
        float4 v4 = make_float4(q[c*4+0]*rn, q[c*4+1]*rn, q[c*4+2]*rn, q[c*4+3]*rn);
        *(float4*)(qb + c*4) = v4;
    }
    const float* kvh = kvs + h*KM*64;
    const float* kth = ktg + h*KM;
    float* zo = znext + (size_t)n*256 + h*64;
    for (int dc = 0; dc < 4; ++dc) {
        float ms[16];
        #pragma unroll
        for (int d = 0; d < 16; ++d) ms[d] = 0.f;
        for (int k = 0; k < 10; ++k) {
            float den = 0.f;
            #pragma unroll
            for (int m = 0; m < 32; ++m) den = fmaf(q[m], kth[k*32+m], den);
            float rd = 1.f / (den * 10.f);
            const float* base = kvh + k*2048 + dc*16;
            #pragma unroll
            for (int m = 0; m < 32; ++m) {
                float qm = q[m] * rd;
                #pragma unroll
                for (int d = 0; d < 16; ++d)
                    ms[d] = fmaf(qm, base[m*64 + d], ms[d]);
            }
        }
        #pragma unroll
        for (int d = 0; d < 16; ++d) zo[dc*16 + d] = ms[d];
    }
}

// ---------- A[e,h] = dot32(qpn[end], kp[start])
__global__ void k_edge(const int* __restrict__ ei, const float* __restrict__ qpn,
                       const float* __restrict__ kpb, float* __restrict__ A) {
    int gid = blockIdx.x*256 + threadIdx.x;
    int e = gid >> 2, h = gid & 3;
    int s = ei[e];
    int d = ei[EE + e];
    const float4* qr = (const float4*)(qpn + (size_t)d*128 + h*32);
    const float4* kr = (const float4*)(kpb + (size_t)s*128 + h*32);
    float acc = 0.f;
    #pragma unroll
    for (int c = 0; c < 8; ++c) {
        float4 a = qr[c], b = kr[c];
        acc += a.x*b.x + a.y*b.y + a.z*b.z + a.w*b.w;
    }
    A[gid] = acc;
}

// ---------- vr[row] = rsd[row] * v[row], bf16-compressed (halves conv gather traffic)
__global__ __launch_bounds__(256) void k_vr(const float* __restrict__ vbuf,
                      const float* __restrict__ rsd, unsigned short* __restrict__ vr) {
    int t = threadIdx.x;
    int row = blockIdx.x*4 + (t >> 6);
    int lane = t & 63;
    float rs = rsd[row];
    float4 v4 = *(const float4*)(vbuf + (size_t)row*256 + lane*4);
    ushort4 o;
    o.x = f2bf(rs * v4.x);
    o.y = f2bf(rs * v4.y);
    o.z = f2bf(rs * v4.z);
    o.w = f2bf(rs * v4.w);
    *(ushort4*)(vr + (size_t)row*256 + lane*4) = o;
}

// ---------- conv (CSR gather, bf16): znext[col] += sig_h*rsqrt(din[col]) * sum_e vr[row]
__global__ __launch_bounds__(256) void k_conv_csr(const int* __restrict__ offsets,
                        const int* __restrict__ csr_row, const int* __restrict__ din,
                        const unsigned short* __restrict__ vr,
                        const float* __restrict__ brb, float* __restrict__ znext) {
    int t = threadIdx.x;
    int w = t >> 6, lane = t & 63;
    int col = blockIdx.x*4 + w;
    if (col >= NN) return;
    int s0 = offsets[col], s1 = offsets[col+1];
    if (s0 == s1) return;
    float a0 = 0.f, a1 = 0.f, a2 = 0.f, a3 = 0.f;
    for (int j = s0; j < s1; ++j) {
        int row = csr_row[j];
        ushort4 u = *(const ushort4*)(vr + (size_t)row*256 + lane*4);
        a0 += bf2f(u.x);
        a1 += bf2f(u.y);
        a2 += bf2f(u.z);
        a3 += bf2f(u.w);
    }
    int h = lane >> 4;
    float sig = 1.f / (1.f + __expf(-brb[h]));
    float sc = sig * rsqrtf((float)din[col]);
    float* zp = znext + (size_t)col*256 + lane*4;
    float4 zv = *(float4*)zp;
    zv.x += sc*a0; zv.y += sc*a1; zv.z += sc*a2; zv.w += sc*a3;
    *(float4*)zp = zv;
}

// ---------- out[n][o] = sum_f znext[n][f] * Wo[o][f] + Wob[o]
__global__ __launch_bounds__(256) void k_out(const float* __restrict__ znext, const float* __restrict__ WoT,
                      const float* __restrict__ Wob, float* __restrict__ out) {
    int n = blockIdx.x*256 + threadIdx.x;
    if (n >= NN) return;
    float acc[64];
    #pragma unroll
    for (int o = 0; o < 64; ++o) acc[o] = Wob[o];
    const float* zr = znext + (size_t)n*256;
    for (int fc = 0; fc < 64; ++fc) {
        float4 z4 = *(const float4*)(zr + fc*4);
        float zz[4] = {z4.x, z4.y, z4.z, z4.w};
        #pragma unroll
        for (int j = 0; j < 4; ++j) {
            const float* wr = WoT + (fc*4+j)*64;
            #pragma unroll
            for (int o = 0; o < 64; ++o)
                acc[o] = fmaf(zz[j], wr[o], acc[o]);
        }
    }
    float* ob = out + (size_t)n*64;
    #pragma unroll
    for (int o = 0; o < 64; ++o) ob[o] = acc[o];
}

extern "C" void kernel_launch(void* const* d_in, const int* in_sizes, int n_in,
                              void* d_out, int out_size, void* d_ws, size_t ws_size,
                              hipStream_t stream) {
    const float* z    = (const float*)d_in[0];
    const int*   ei   = (const int*)d_in[1];
    const float* Wq   = (const float*)d_in[2];
    const float* Wqb  = (const float*)d_in[3];
    const float* Wk   = (const float*)d_in[4];
    const float* Wkb  = (const float*)d_in[5];
    const float* Wv   = (const float*)d_in[6];
    const float* Wvb  = (const float*)d_in[7];
    const float* Wo   = (const float*)d_in[8];
    const float* Wob  = (const float*)d_in[9];
    const float* brb  = (const float*)d_in[10];
    const float* proj = (const float*)d_in[11];
    const float* g    = (const float*)d_in[12];
    float* out = (float*)d_out;
    float* A   = out + (size_t)NN*64;
    float* ws  = (float*)d_ws;

    float* Wt      = ws;                 // 131072
    float* bext    = ws + 131072;        // 1024
    float* WoT     = ws + 132096;        // 16384
    float* kvs     = ws + 148480;        // 81920
    float* ktg     = ws + 230400;        // 1280
    float* kp_sum  = ws + 231680;        // 128
    unsigned* stab = (unsigned*)(ws + 231808); // 4
    int* din       = (int*)(ws + 231812);      // 50000
    int* dout_     = (int*)(ws + 281812);      // 50000
    float* vbuf    = ws + 331840;        // 12.8M
    float* qp      = ws + 13131840;      // 6.4M
    float* kpb     = ws + 19531840;      // 6.4M
    float* znext   = ws + 25931840;      // 12.8M
    // small scan scratch after znext (~0.6 MB)
    int* offsets   = (int*)(ws + 38731840);    // 50001 (pad to 50004)
    int* cursor    = (int*)(ws + 38781844);    // 50000
    int* bsum      = (int*)(ws + 38831844);    // 196
    int* boff      = (int*)(ws + 38832040);    // 196
    float* rsd     = ws + 38832236;            // 50000 -> end 38882236 floats (~155.5 MB)
    // aliases:
    //   vT  (256 x 50176 bf16 = 25.7MB) -> znext region (dead until k_znext, which
    //        fully overwrites it after k_kvs has consumed vT)
    //   csr_row (800000 ints) -> kpb (dead after k_edge)
    //   vr  (12.8M bf16)      -> qp  (dead after k_edge)
    unsigned short* vT  = (unsigned short*)znext;
    int* csr_row        = (int*)kpb;
    unsigned short* vr  = (unsigned short*)qp;

    hipMemsetAsync(ws + 148480, 0, (size_t)(331840 - 148480)*sizeof(float), stream);
    k_prep<<<128, 256, 0, stream>>>(Wq, Wqb, Wk, Wkb, Wv, Wvb, Wo, proj, Wt, bext, WoT);
    k_ztail<<<88, 256, 0, stream>>>((unsigned*)vT);
    k_qkv<<<3125, 256, 0, stream>>>(z, Wt, bext, vbuf, qp, kpb, stab, vT);
    k_deg<<<3125, 256, 0, stream>>>(ei, din, dout_);
    k_rs<<<196, 256, 0, stream>>>(dout_, rsd);
    k_scan_part<<<196, 256, 0, stream>>>(din, bsum);
    k_scan_top<<<1, 64, 0, stream>>>(bsum, boff);
    k_scan_fin<<<196, 256, 0, stream>>>(din, boff, offsets, cursor);
    k_kp<<<512, 256, 0, stream>>>(kpb, stab, kp_sum);
    k_kvs<<<dim3(KVSNB, 4), 256, 0, stream>>>(kpb, g, vT, kvs, ktg);
    k_znext<<<dim3(196,4), 256, 0, stream>>>(qp, kvs, ktg, kp_sum, znext);
    k_edge<<<12500, 256, 0, stream>>>(ei, qp, kpb, A);
    k_scatter<<<3125, 256, 0, stream>>>(ei, cursor, csr_row);       // csr_row aliases kpb (dead now)
    k_vr<<<12500, 256, 0, stream>>>(vbuf, rsd, vr);                 // vr aliases qp (dead now)
    k_conv_csr<<<12500, 256, 0, stream>>>(offsets, csr_row, din, vr, brb, znext);
    k_out<<<196, 256, 0, stream>>>(znext, WoT, Wob, out);
}

// Round 8
// 901.057 us; speedup vs baseline: 2.8202x; 1.0420x over previous
//
#include <hip/hip_runtime.h>

#define NN 50000
#define EE 800000
#define IND 128
#define NCOL 1024
#define KM 320            // K * Mpad = 10*32
#define M30 30
#define RATIO 0.1825741858f   // 30^-0.5
#define EPSF 1e-6f
#define QKSCALE 0.7071067812f // (1/sqrt(0.25)) * 64^-0.25
#define VTS 50176             // vT row stride (196*256)
#define KVSNB 196             // k_kvs node-chunk blocks (256 nodes each)
#define AST 136               // a-tile LDS row stride in bf16 (2-way-free banks)

typedef __attribute__((ext_vector_type(8))) short bf16x8;
typedef __attribute__((ext_vector_type(4))) float f32x4;

__device__ __forceinline__ unsigned f2s(float f) {
    unsigned u = __float_as_uint(f);
    return (u & 0x80000000u) ? ~u : (u | 0x80000000u);
}
__device__ __forceinline__ float s2f(unsigned s) {
    return __uint_as_float((s & 0x80000000u) ? (s & 0x7fffffffu) : ~s);
}
__device__ __forceinline__ unsigned short f2bf(float f) {   // RTNE fp32->bf16
    unsigned u = __float_as_uint(f);
    unsigned r = u + 0x7fffu + ((u >> 16) & 1u);
    return (unsigned short)(r >> 16);
}
__device__ __forceinline__ float bf2f(unsigned short h) {
    return __uint_as_float(((unsigned)h) << 16);
}

// ---------- prep: Wt[IND][NCOL] (cols: 0-255 s*Wq^T, 256-511 s*Wk^T, 512-767 Wv^T,
// 768-895 Pq[h,m], 896-1023 Pk[h,m]), bias_ext[NCOL], WoT[256][64]
__global__ void k_prep(const float* __restrict__ Wq, const float* __restrict__ Wqb,
                       const float* __restrict__ Wk, const float* __restrict__ Wkb,
                       const float* __restrict__ Wv, const float* __restrict__ Wvb,
                       const float* __restrict__ Wo, const float* __restrict__ proj,
                       float* __restrict__ Wt, float* __restrict__ bext, float* __restrict__ WoT) {
    int i = blockIdx.x;   // 0..127
    int t = threadIdx.x;  // 0..255
    Wt[i*NCOL + t]       = QKSCALE * Wq[t*IND + i];
    Wt[i*NCOL + 256 + t] = QKSCALE * Wk[t*IND + i];
    Wt[i*NCOL + 512 + t] = Wv[t*IND + i];
    {
        const float* W = (t < 128) ? Wq : Wk;
        int c = (t < 128) ? t : (t - 128);
        int h = c >> 5, m = c & 31;
        float val = 0.f;
        if (m < M30) {
            for (int d = 0; d < 64; ++d)
                val += QKSCALE * W[(h*64+d)*IND + i] * proj[m*64 + d];
        }
        Wt[i*NCOL + 768 + t] = val;
    }
    if (t < 128) {
        int f = i*2 + (t >> 6);
        int o = t & 63;
        WoT[f*64 + o] = Wo[o*256 + f];
    }
    if (i == 0) {
        bext[t]       = QKSCALE * Wqb[t];
        bext[256 + t] = QKSCALE * Wkb[t];
        bext[512 + t] = Wvb[t];
        const float* Bb = (t < 128) ? Wqb : Wkb;
        int c = (t < 128) ? t : (t - 128);
        int h = c >> 5, m = c & 31;
        float val = 0.f;
        if (m < M30) {
            for (int d = 0; d < 64; ++d)
                val += QKSCALE * Bb[h*64+d] * proj[m*64 + d];
        }
        bext[768 + t] = val;
    }
}

// ---------- Wcb: bf16 hi/lo split of Wt, layout [col][k] (MFMA B operand)
__global__ void k_prep2(const float* __restrict__ Wt, unsigned short* __restrict__ Wcb) {
    int idx = blockIdx.x*256 + threadIdx.x;   // 512 blocks -> 131072
    int col = idx >> 7, k = idx & 127;
    float f = Wt[k*NCOL + col];
    unsigned short hi = f2bf(f);
    unsigned short lo = f2bf(f - bf2f(hi));
    Wcb[col*128 + k] = hi;
    Wcb[131072 + col*128 + k] = lo;
}

// ---------- zero vT tail cols [50000,50176) (vT aliases znext; replay determinism)
__global__ void k_ztail(unsigned* __restrict__ vT32) {
    int idx = blockIdx.x*256 + threadIdx.x;  // 88 blocks * 256 = 22528 = 256*88
    int row = idx / 88, c = idx - row*88;
    vT32[(size_t)row * (VTS/2) + (50000/2) + c] = 0u;
}

// ---------- fused QKV+dash GEMM via bf16x3 MFMA (fp32-equivalent accuracy).
// Block = 64 nodes, 4 chunks of 256 cols (q,k,v,dash); wave w = 64-col slice.
// chunk0/1: wave w == head w -> diag via shfl reduce -> LDS.
// chunk2: v -> vbuf. chunk3: waves 0,1 -> qp (rowmax+diag_q); waves 2,3 -> kpb raw + stab.
__global__ __launch_bounds__(256) void k_qkv_mfma(const float* __restrict__ z,
                      const unsigned short* __restrict__ Wcb, const float* __restrict__ bext,
                      float* __restrict__ vbuf, float* __restrict__ qp, float* __restrict__ kpb,
                      unsigned* __restrict__ stab) {
    __shared__ __align__(16) unsigned short a_hi[64*AST];
    __shared__ __align__(16) unsigned short a_lo[64*AST];
    __shared__ float diag_l[2][4][64];   // [q/k][head][node]
    int t = threadIdx.x;
    int n0 = blockIdx.x * 64;
    int w = t >> 6, lane = t & 63;
    // ---- stage z -> LDS bf16 hi/lo (node = t>>2, k-range (t&3)*32..+31)
    {
        int node = t >> 2, ks = (t & 3) * 32;
        bool ok = (n0 + node) < NN;
        const float* zr = z + (size_t)(n0 + node)*IND + ks;
        unsigned hbuf[16], lbuf[16];
        #pragma unroll
        for (int c = 0; c < 8; ++c) {
            float4 v = ok ? *(const float4*)(zr + c*4) : make_float4(0.f,0.f,0.f,0.f);
            float fv[4] = {v.x, v.y, v.z, v.w};
            unsigned short h2[4], l2[4];
            #pragma unroll
            for (int j = 0; j < 4; ++j) {
                h2[j] = f2bf(fv[j]);
                l2[j] = f2bf(fv[j] - bf2f(h2[j]));
            }
            hbuf[c*2]   = (unsigned)h2[0] | ((unsigned)h2[1] << 16);
            hbuf[c*2+1] = (unsigned)h2[2] | ((unsigned)h2[3] << 16);
            lbuf[c*2]   = (unsigned)l2[0] | ((unsigned)l2[1] << 16);
            lbuf[c*2+1] = (unsigned)l2[2] | ((unsigned)l2[3] << 16);
        }
        uint4* hp = (uint4*)(&a_hi[node*AST + ks]);
        uint4* lp = (uint4*)(&a_lo[node*AST + ks]);
        #pragma unroll
        for (int c = 0; c < 4; ++c) {
            hp[c] = make_uint4(hbuf[c*4], hbuf[c*4+1], hbuf[c*4+2], hbuf[c*4+3]);
            lp[c] = make_uint4(lbuf[c*4], lbuf[c*4+1], lbuf[c*4+2], lbuf[c*4+3]);
        }
    }
    __syncthreads();
    int arow = lane & 15;
    int ao = (lane >> 4) * 8;
    for (int c = 0; c < 4; ++c) {
        int colbase = c*256 + w*64;
        f32x4 acc[4][4];
        #pragma unroll
        for (int mt = 0; mt < 4; ++mt)
            #pragma unroll
            for (int nt = 0; nt < 4; ++nt)
                acc[mt][nt] = (f32x4){0.f,0.f,0.f,0.f};
        #pragma unroll
        for (int ks = 0; ks < 4; ++ks) {
            int ko = ks*32 + ao;
            bf16x8 Ah[4], Al[4];
            #pragma unroll
            for (int mt = 0; mt < 4; ++mt) {
                Ah[mt] = *(const bf16x8*)(&a_hi[(mt*16 + arow)*AST + ko]);
                Al[mt] = *(const bf16x8*)(&a_lo[(mt*16 + arow)*AST + ko]);
            }
            #pragma unroll
            for (int nt = 0; nt < 4; ++nt) {
                const unsigned short* bp = Wcb + (size_t)(colbase + nt*16 + arow)*128 + ko;
                bf16x8 Bh = *(const bf16x8*)bp;
                bf16x8 Bl = *(const bf16x8*)(bp + 131072);
                #pragma unroll
                for (int mt = 0; mt < 4; ++mt) {
                    acc[mt][nt] = __builtin_amdgcn_mfma_f32_16x16x32_bf16(Ah[mt], Bh, acc[mt][nt], 0, 0, 0);
                    acc[mt][nt] = __builtin_amdgcn_mfma_f32_16x16x32_bf16(Ah[mt], Bl, acc[mt][nt], 0, 0, 0);
                    acc[mt][nt] = __builtin_amdgcn_mfma_f32_16x16x32_bf16(Al[mt], Bh, acc[mt][nt], 0, 0, 0);
                }
            }
        }
        // bias (per col)
        float bv[4];
        #pragma unroll
        for (int nt = 0; nt < 4; ++nt) bv[nt] = bext[colbase + nt*16 + arow];
        #pragma unroll
        for (int mt = 0; mt < 4; ++mt)
            #pragma unroll
            for (int nt = 0; nt < 4; ++nt)
                #pragma unroll
                for (int r = 0; r < 4; ++r)
                    acc[mt][nt][r] += bv[nt];
        // D layout: row = 16mt + (lane>>4)*4 + r, col = 16nt + (lane&15)
        if (c < 2) {
            // diag[head=w][node] = 0.5 * sum over wave's 64 cols
            #pragma unroll
            for (int mt = 0; mt < 4; ++mt) {
                #pragma unroll
                for (int r = 0; r < 4; ++r) {
                    float s = 0.f;
                    #pragma unroll
                    for (int nt = 0; nt < 4; ++nt) s += acc[mt][nt][r]*acc[mt][nt][r];
                    s += __shfl_xor(s, 1); s += __shfl_xor(s, 2);
                    s += __shfl_xor(s, 4); s += __shfl_xor(s, 8);
                    if (arow == 0) diag_l[c][w][mt*16 + (lane>>4)*4 + r] = 0.5f*s;
                }
            }
        } else if (c == 2) {
            #pragma unroll
            for (int mt = 0; mt < 4; ++mt)
                #pragma unroll
                for (int r = 0; r < 4; ++r) {
                    int node = n0 + mt*16 + (lane>>4)*4 + r;
                    if (node < NN) {
                        #pragma unroll
                        for (int nt = 0; nt < 4; ++nt)
                            vbuf[(size_t)node*256 + w*64 + nt*16 + arow] = acc[mt][nt][r];
                    }
                }
        } else {
            int hh = (w & 1) * 2;
            if (w < 2) {
                // q-dash -> qp
                #pragma unroll
                for (int p = 0; p < 2; ++p) {
                    int h = hh + p;
                    #pragma unroll
                    for (int mt = 0; mt < 4; ++mt) {
                        #pragma unroll
                        for (int r = 0; r < 4; ++r) {
                            int row = mt*16 + (lane>>4)*4 + r;
                            float dg = diag_l[0][h][row];
                            float mx = fmaxf(acc[mt][2*p][r],
                                             (arow < 14) ? acc[mt][2*p+1][r] : -3.0e38f);
                            mx = fmaxf(mx, __shfl_xor(mx, 1)); mx = fmaxf(mx, __shfl_xor(mx, 2));
                            mx = fmaxf(mx, __shfl_xor(mx, 4)); mx = fmaxf(mx, __shfl_xor(mx, 8));
                            int node = n0 + row;
                            if (node < NN) {
                                #pragma unroll
                                for (int q2 = 0; q2 < 2; ++q2) {
                                    int m = q2*16 + arow;
                                    float val = 0.f;
                                    if (m < M30)
                                        val = RATIO * (__expf(acc[mt][2*p+q2][r] - dg - mx) + EPSF);
                                    qp[(size_t)node*128 + h*32 + m] = val;
                                }
                            }
                        }
                    }
                }
            } else {
                // k-dash -> kpb raw + stab
                #pragma unroll
                for (int p = 0; p < 2; ++p) {
                    int h = hh + p;
                    float smax = -3.0e38f;
                    #pragma unroll
                    for (int mt = 0; mt < 4; ++mt) {
                        #pragma unroll
                        for (int r = 0; r < 4; ++r) {
                            int row = mt*16 + (lane>>4)*4 + r;
                            float dg = diag_l[1][h][row];
                            int node = n0 + row;
                            if (node < NN) {
                                #pragma unroll
                                for (int q2 = 0; q2 < 2; ++q2) {
                                    int m = q2*16 + arow;
                                    float d = acc[mt][2*p+q2][r];
                                    bool valid = (m < M30);
                                    kpb[(size_t)node*128 + h*32 + m] = valid ? (d - dg) : 0.f;
                                    if (valid) smax = fmaxf(smax, d);
                                }
                            }
                        }
                    }
                    smax = fmaxf(smax, __shfl_xor(smax, 1));  smax = fmaxf(smax, __shfl_xor(smax, 2));
                    smax = fmaxf(smax, __shfl_xor(smax, 4));  smax = fmaxf(smax, __shfl_xor(smax, 8));
                    smax = fmaxf(smax, __shfl_xor(smax, 16)); smax = fmaxf(smax, __shfl_xor(smax, 32));
                    if (lane == 0) atomicMax(&stab[h], f2s(smax));
                }
            }
        }
        __syncthreads();
    }
}

// ---------- vT[c][n] = bf16(vbuf[n][c]) tiled transpose (64x64 tiles via LDS)
__global__ __launch_bounds__(256) void k_vt(const float* __restrict__ vbuf,
                      unsigned short* __restrict__ vT) {
    __shared__ unsigned short tile[64][72];
    int t = threadIdx.x;
    int n0 = blockIdx.x * 64;
    int c0 = blockIdx.y * 64;
    {
        int node = t >> 2, cs = (t & 3) * 16;
        bool ok = (n0 + node) < NN;
        const float* vr = vbuf + (size_t)(n0 + node)*256 + c0 + cs;
        #pragma unroll
        for (int cc = 0; cc < 4; ++cc) {
            float4 v = ok ? *(const float4*)(vr + cc*4) : make_float4(0.f,0.f,0.f,0.f);
            unsigned u0 = (unsigned)f2bf(v.x) | ((unsigned)f2bf(v.y) << 16);
            unsigned u1 = (unsigned)f2bf(v.z) | ((unsigned)f2bf(v.w) << 16);
            *(unsigned*)(&tile[node][cs + cc*4])     = u0;
            *(unsigned*)(&tile[node][cs + cc*4 + 2]) = u1;
        }
    }
    __syncthreads();
    {
        int d = t >> 2, ns = (t & 3) * 16;
        unsigned ob[8];
        #pragma unroll
        for (int i = 0; i < 8; ++i) {
            unsigned short a = tile[ns + i*2][d];
            unsigned short b = tile[ns + i*2 + 1][d];
            ob[i] = (unsigned)a | ((unsigned)b << 16);
        }
        unsigned short* op = vT + (size_t)(c0 + d)*VTS + n0 + ns;
        *(uint4*)(op)     = make_uint4(ob[0], ob[1], ob[2], ob[3]);
        *(uint4*)(op + 8) = make_uint4(ob[4], ob[5], ob[6], ob[7]);
    }
}

__global__ void k_deg(const int* __restrict__ ei, int* __restrict__ din, int* __restrict__ dout) {
    int e = blockIdx.x*256 + threadIdx.x;
    if (e < EE) {
        atomicAdd(&dout[ei[e]], 1);
        atomicAdd(&din[ei[EE + e]], 1);
    }
}

// rsdout[n] = dout>0 ? rsqrt(dout) : 0
__global__ void k_rs(const int* __restrict__ dout, float* __restrict__ rsd) {
    int i = blockIdx.x*256 + threadIdx.x;
    if (i < NN) {
        int d = dout[i];
        rsd[i] = d > 0 ? rsqrtf((float)d) : 0.f;
    }
}

// ---------- prefix sum over din (3-kernel scan) ----------
__global__ void k_scan_part(const int* __restrict__ din, int* __restrict__ bsum) {
    __shared__ int red[256];
    int t = threadIdx.x;
    int i = blockIdx.x*256 + t;
    red[t] = (i < NN) ? din[i] : 0;
    __syncthreads();
    for (int off = 128; off >= 1; off >>= 1) {
        if (t < off) red[t] += red[t+off];
        __syncthreads();
    }
    if (t == 0) bsum[blockIdx.x] = red[0];
}
__global__ void k_scan_top(const int* __restrict__ bsum, int* __restrict__ boff) {
    if (threadIdx.x == 0) {
        int acc = 0;
        for (int b = 0; b < 196; ++b) { boff[b] = acc; acc += bsum[b]; }
    }
}
__global__ void k_scan_fin(const int* __restrict__ din, const int* __restrict__ boff,
                           int* __restrict__ offsets, int* __restrict__ cursor) {
    __shared__ int s[256];
    int t = threadIdx.x;
    int i = blockIdx.x*256 + t;
    int v = (i < NN) ? din[i] : 0;
    s[t] = v;
    __syncthreads();
    for (int off = 1; off < 256; off <<= 1) {
        int add = (t >= off) ? s[t-off] : 0;
        __syncthreads();
        s[t] += add;
        __syncthreads();
    }
    int excl = s[t] - v + boff[blockIdx.x];
    if (i < NN) { offsets[i] = excl; cursor[i] = excl; }
    if (i == NN-1) offsets[NN] = excl + v;
}

// scatter edge rows into CSR-by-col order
__global__ void k_scatter(const int* __restrict__ ei, int* __restrict__ cursor,
                          int* __restrict__ csr_row) {
    int e = blockIdx.x*256 + threadIdx.x;
    if (e < EE) {
        int col = ei[EE + e];
        int pos = atomicAdd(&cursor[col], 1);
        csr_row[pos] = ei[e];
    }
}

// ---------- finish kp = ratio*(exp(dash-diag-stab)+eps) in place; accumulate kp_sum[h][m]
__global__ void k_kp(float* __restrict__ kpb, const unsigned* __restrict__ stab,
                     float* __restrict__ kp_sum) {
    __shared__ float red[256];
    int t = threadIdx.x;
    int hm = t & 127;
    int h = hm >> 5, m = hm & 31;
    float st = s2f(stab[h]);
    float ksum = 0.f;
    const int total = NN*128;
    for (int idx = blockIdx.x*256 + t; idx < total; idx += gridDim.x*256) {
        float val = kpb[idx];
        float kpv = 0.f;
        if (m < M30) kpv = RATIO * (__expf(val - st) + EPSF);
        kpb[idx] = kpv;
        ksum += kpv;
    }
    red[t] = ksum;
    __syncthreads();
    if (t < 128) atomicAdd(&kp_sum[hm], red[t] + red[t+128]);
}

// ---------- kvs[h][km][d] = sum_n w[n,km]*v[n,d] via MFMA (16x16x32 bf16).
__global__ __launch_bounds__(256) void k_kvs(const float* __restrict__ kpb,
                      const float* __restrict__ g, const unsigned short* __restrict__ vT,
                      float* __restrict__ kvs, float* __restrict__ ktg) {
    __shared__ __align__(16) unsigned short w_l[320*40]; // row stride 40 bf16 (80B)
    __shared__ __align__(16) unsigned short v_l[64*40];
    __shared__ __align__(16) float eg_l[10][36];
    int t = threadIdx.x;
    int h = blockIdx.y;
    int n0b = blockIdx.x * 256;
    int lane = t & 63;
    int wb = (t >> 6) * 80;            // wave's km base
    int arow = lane & 15;
    int acol = (lane >> 4) * 8;        // bf16 col offset of the 8-elem fragment
    f32x4 acc[5][4];
    #pragma unroll
    for (int kt = 0; kt < 5; ++kt)
        #pragma unroll
        for (int dt = 0; dt < 4; ++dt)
            acc[kt][dt] = (f32x4){0.f, 0.f, 0.f, 0.f};
    float wsum0 = 0.f, wsum1 = 0.f;
    int k0 = t >> 5, m0 = t & 31;      // row t = k0*32 + m0
    int k1 = 8 + (t >> 5), m1 = t & 31; // row t+256 (t<64)

    for (int st = 0; st < 8; ++st) {
        int n0 = n0b + st * 32;
        __syncthreads();               // prev tile consumed by MFMA
        // ---- stage eg[k][n] (fp32, broadcast-read layout)
        #pragma unroll
        for (int i = 0; i < 2; ++i) {
            int flat = t + i*256;
            if (flat < 320) {
                int kk = flat % 10, n = flat / 10;
                float e = 0.f;
                if (n0 + n < NN) e = __expf(g[(size_t)(n0+n)*40 + h*10 + kk]);
                eg_l[kk][n] = e;
            }
        }
        // ---- stage v tile (bf16 direct from vT; tail cols zeroed by k_ztail/k_vt)
        {
            int d = t >> 2, seg = t & 3;
            uint4 vv = *(const uint4*)(vT + (size_t)(h*64 + d)*VTS + n0 + seg*8);
            *(uint4*)(&v_l[d*40 + seg*8]) = vv;
        }
        __syncthreads();
        // ---- build w rows (bf16) + wsum from rounded values
        {
            const float* kprow = kpb + (size_t)n0*128 + h*32;
            bool full = (n0 + 32 <= NN);
            // row t
            {
                unsigned dw[16];
                float s = 0.f;
                #pragma unroll
                for (int c = 0; c < 16; ++c) {
                    int na = c*2, nb = c*2 + 1;
                    float kpa = 0.f, kpc = 0.f;
                    if (full) {
                        kpa = kprow[(size_t)na*128 + m0];
                        kpc = kprow[(size_t)nb*128 + m0];
                    } else {
                        if (n0 + na < NN) kpa = kprow[(size_t)na*128 + m0];
                        if (n0 + nb < NN) kpc = kprow[(size_t)nb*128 + m0];
                    }
                    unsigned ua = __float_as_uint(kpa * eg_l[k0][na]);
                    unsigned ub = __float_as_uint(kpc * eg_l[k0][nb]);
                    s += __uint_as_float(ua & 0xFFFF0000u) + __uint_as_float(ub & 0xFFFF0000u);
                    dw[c] = (ua >> 16) | (ub & 0xFFFF0000u);
                }
                wsum0 += s;
                uint4* wp = (uint4*)(&w_l[t*40]);
                wp[0] = make_uint4(dw[0], dw[1], dw[2],  dw[3]);
                wp[1] = make_uint4(dw[4], dw[5], dw[6],  dw[7]);
                wp[2] = make_uint4(dw[8], dw[9], dw[10], dw[11]);
                wp[3] = make_uint4(dw[12],dw[13],dw[14], dw[15]);
            }
            // row t+256
            if (t < 64) {
                unsigned dw[16];
                float s = 0.f;
                #pragma unroll
                for (int c = 0; c < 16; ++c) {
                    int na = c*2, nb = c*2 + 1;
                    float kpa = 0.f, kpc = 0.f;
                    if (full) {
                        kpa = kprow[(size_t)na*128 + m1];
                        kpc = kprow[(size_t)nb*128 + m1];
                    } else {
                        if (n0 + na < NN) kpa = kprow[(size_t)na*128 + m1];
                        if (n0 + nb < NN) kpc = kprow[(size_t)nb*128 + m1];
                    }
                    unsigned ua = __float_as_uint(kpa * eg_l[k1][na]);
                    unsigned ub = __float_as_uint(kpc * eg_l[k1][nb]);
                    s += __uint_as_float(ua & 0xFFFF0000u) + __uint_as_float(ub & 0xFFFF0000u);
                    dw[c] = (ua >> 16) | (ub & 0xFFFF0000u);
                }
                wsum1 += s;
                uint4* wp = (uint4*)(&w_l[(t + 256)*40]);
                wp[0] = make_uint4(dw[0], dw[1], dw[2],  dw[3]);
                wp[1] = make_uint4(dw[4], dw[5], dw[6],  dw[7]);
                wp[2] = make_uint4(dw[8], dw[9], dw[10], dw[11]);
                wp[3] = make_uint4(dw[12],dw[13],dw[14], dw[15]);
            }
        }
        __syncthreads();
        // ---- MFMA: 4 B-frags shared across 5 A-tiles
        bf16x8 Bf[4];
        #pragma unroll
        for (int dt = 0; dt < 4; ++dt)
            Bf[dt] = *(const bf16x8*)(&v_l[(dt*16 + arow)*40 + acol]);
        #pragma unroll
        for (int kt = 0; kt < 5; ++kt) {
            bf16x8 Af = *(const bf16x8*)(&w_l[(wb + kt*16 + arow)*40 + acol]);
            #pragma unroll
            for (int dt = 0; dt < 4; ++dt)
                acc[kt][dt] = __builtin_amdgcn_mfma_f32_16x16x32_bf16(Af, Bf[dt], acc[kt][dt], 0, 0, 0);
        }
    }
    // ---- epilogue: D lane mapping col=lane&15, row=(lane>>4)*4+reg
    {
        int orow = (lane >> 4) * 4;
        int ocol = lane & 15;
        float* kb = kvs + h*KM*64;
        #pragma unroll
        for (int kt = 0; kt < 5; ++kt)
            #pragma unroll
            for (int dt = 0; dt < 4; ++dt)
                #pragma unroll
                for (int r = 0; r < 4; ++r)
                    atomicAdd(&kb[(wb + kt*16 + orow + r)*64 + dt*16 + ocol], acc[kt][dt][r]);
        atomicAdd(&ktg[h*KM + t], wsum0);
        if (t < 64) atomicAdd(&ktg[h*KM + 256 + t], wsum1);
    }
}

// ---------- per node: norm/qpn (in place), z_den per k, z_next = mean_k(num/den)
__global__ __launch_bounds__(256) void k_znext(float* __restrict__ qp, const float* __restrict__ kvs,
                        const float* __restrict__ ktg, const float* __restrict__ kp_sum,
                        float* __restrict__ znext) {
    int t = threadIdx.x;
    int n = blockIdx.x*256 + t;
    int h = blockIdx.y;
    if (n >= NN) return;
    float q[32];
    float* qb = qp + (size_t)n*128 + h*32;
    #pragma unroll
    for (int c = 0; c < 8; ++c) {
        float4 v4 = *(const float4*)(qb + c*4);
        q[c*4+0]=v4.x; q[c*4+1]=v4.y; q[c*4+2]=v4.z; q[c*4+3]=v4.w;
    }
    const float* ks = kp_sum + h*32;
    float norm = 0.f;
    #pragma unroll
    for (int m = 0; m < 32; ++m) norm = fmaf(q[m], ks[m], norm);
    float rn = 1.f / norm;
    #pragma unroll
    for (int c = 0; c < 8; ++c) {
        float4 v4 = make_float4(q[c*4+0]*rn, q[c*4+1]*rn, q[c*4+2]*rn, q[c*4+3]*rn);
        *(float4*)(qb + c*4) = v4;
    }
    const float* kvh = kvs + h*KM*64;
    const float* kth = ktg + h*KM;
    float* zo = znext + (size_t)n*256 + h*64;
    for (int dc = 0; dc < 4; ++dc) {
        float ms[16];
        #pragma unroll
        for (int d = 0; d < 16; ++d) ms[d] = 0.f;
        for (int k = 0; k < 10; ++k) {
            float den = 0.f;
            #pragma unroll
            for (int m = 0; m < 32; ++m) den = fmaf(q[m], kth[k*32+m], den);
            float rd = 1.f / (den * 10.f);
            const float* base = kvh + k*2048 + dc*16;
            #pragma unroll
            for (int m = 0; m < 32; ++m) {
                float qm = q[m] * rd;
                #pragma unroll
                for (int d = 0; d < 16; ++d)
                    ms[d] = fmaf(qm, base[m*64 + d], ms[d]);
            }
        }
        #pragma unroll
        for (int d = 0; d < 16; ++d) zo[dc*16 + d] = ms[d];
    }
}

// ---------- A[e,h] = dot32(qpn[end], kp[start])
__global__ void k_edge(const int* __restrict__ ei, const float* __restrict__ qpn,
                       const float* __restrict__ kpb, float* __restrict__ A) {
    int gid = blockIdx.x*256 + threadIdx.x;
    int e = gid >> 2, h = gid & 3;
    int s = ei[e];
    int d = ei[EE + e];
    const float4* qr = (const float4*)(qpn + (size_t)d*128 + h*32);
    const float4* kr = (const float4*)(kpb + (size_t)s*128 + h*32);
    float acc = 0.f;
    #pragma unroll
    for (int c = 0; c < 8; ++c) {
        float4 a = qr[c], b = kr[c];
        acc += a.x*b.x + a.y*b.y + a.z*b.z + a.w*b.w;
    }
    A[gid] = acc;
}

// ---------- vr[row] = rsd[row] * v[row], bf16-compressed (halves conv gather traffic)
__global__ __launch_bounds__(256) void k_vr(const float* __restrict__ vbuf,
                      const float* __restrict__ rsd, unsigned short* __restrict__ vr) {
    int t = threadIdx.x;
    int row = blockIdx.x*4 + (t >> 6);
    int lane = t & 63;
    float rs = rsd[row];
    float4 v4 = *(const float4*)(vbuf + (size_t)row*256 + lane*4);
    ushort4 o;
    o.x = f2bf(rs * v4.x);
    o.y = f2bf(rs * v4.y);
    o.z = f2bf(rs * v4.z);
    o.w = f2bf(rs * v4.w);
    *(ushort4*)(vr + (size_t)row*256 + lane*4) = o;
}

// ---------- conv (CSR gather, bf16): znext[col] += sig_h*rsqrt(din[col]) * sum_e vr[row]
__global__ __launch_bounds__(256) void k_conv_csr(const int* __restrict__ offsets,
                        const int* __restrict__ csr_row, const int* __restrict__ din,
                        const unsigned short* __restrict__ vr,
                        const float* __restrict__ brb, float* __restrict__ znext) {
    int t = threadIdx.x;
    int w = t >> 6, lane = t & 63;
    int col = blockIdx.x*4 + w;
    if (col >= NN) return;
    int s0 = offsets[col], s1 = offsets[col+1];
    if (s0 == s1) return;
    float a0 = 0.f, a1 = 0.f, a2 = 0.f, a3 = 0.f;
    for (int j = s0; j < s1; ++j) {
        int row = csr_row[j];
        ushort4 u = *(const ushort4*)(vr + (size_t)row*256 + lane*4);
        a0 += bf2f(u.x);
        a1 += bf2f(u.y);
        a2 += bf2f(u.z);
        a3 += bf2f(u.w);
    }
    int h = lane >> 4;
    float sig = 1.f / (1.f + __expf(-brb[h]));
    float sc = sig * rsqrtf((float)din[col]);
    float* zp = znext + (size_t)col*256 + lane*4;
    float4 zv = *(float4*)zp;
    zv.x += sc*a0; zv.y += sc*a1; zv.z += sc*a2; zv.w += sc*a3;
    *(float4*)zp = zv;
}

// ---------- out[n][o] = sum_f znext[n][f] * Wo[o][f] + Wob[o]
__global__ __launch_bounds__(256) void k_out(const float* __restrict__ znext, const float* __restrict__ WoT,
                      const float* __restrict__ Wob, float* __restrict__ out) {
    int n = blockIdx.x*256 + threadIdx.x;
    if (n >= NN) return;
    float acc[64];
    #pragma unroll
    for (int o = 0; o < 64; ++o) acc[o] = Wob[o];
    const float* zr = znext + (size_t)n*256;
    for (int fc = 0; fc < 64; ++fc) {
        float4 z4 = *(const float4*)(zr + fc*4);
        float zz[4] = {z4.x, z4.y, z4.z, z4.w};
        #pragma unroll
        for (int j = 0; j < 4; ++j) {
            const float* wr = WoT + (fc*4+j)*64;
            #pragma unroll
            for (int o = 0; o < 64; ++o)
                acc[o] = fmaf(zz[j], wr[o], acc[o]);
        }
    }
    float* ob = out + (size_t)n*64;
    #pragma unroll
    for (int o = 0; o < 64; ++o) ob[o] = acc[o];
}

extern "C" void kernel_launch(void* const* d_in, const int* in_sizes, int n_in,
                              void* d_out, int out_size, void* d_ws, size_t ws_size,
                              hipStream_t stream) {
    const float* z    = (const float*)d_in[0];
    const int*   ei   = (const int*)d_in[1];
    const float* Wq   = (const float*)d_in[2];
    const float* Wqb  = (const float*)d_in[3];
    const float* Wk   = (const float*)d_in[4];
    const float* Wkb  = (const float*)d_in[5];
    const float* Wv   = (const float*)d_in[6];
    const float* Wvb  = (const float*)d_in[7];
    const float* Wo   = (const float*)d_in[8];
    const float* Wob  = (const float*)d_in[9];
    const float* brb  = (const float*)d_in[10];
    const float* proj = (const float*)d_in[11];
    const float* g    = (const float*)d_in[12];
    float* out = (float*)d_out;
    float* A   = out + (size_t)NN*64;
    float* ws  = (float*)d_ws;

    float* Wt      = ws;                 // 131072
    float* bext    = ws + 131072;        // 1024
    float* WoT     = ws + 132096;        // 16384
    float* kvs     = ws + 148480;        // 81920
    float* ktg     = ws + 230400;        // 1280
    float* kp_sum  = ws + 231680;        // 128
    unsigned* stab = (unsigned*)(ws + 231808); // 4
    int* din       = (int*)(ws + 231812);      // 50000
    int* dout_     = (int*)(ws + 281812);      // 50000
    float* vbuf    = ws + 331840;        // 12.8M
    float* qp      = ws + 13131840;      // 6.4M
    float* kpb     = ws + 19531840;      // 6.4M
    float* znext   = ws + 25931840;      // 12.8M
    int* offsets   = (int*)(ws + 38731840);    // 50001 (pad to 50004)
    int* cursor    = (int*)(ws + 38781844);    // 50000
    int* bsum      = (int*)(ws + 38831844);    // 196
    int* boff      = (int*)(ws + 38832040);    // 196
    float* rsd     = ws + 38832236;            // 50000 -> 38882236
    unsigned short* Wcb = (unsigned short*)(ws + 38882240); // 262144 ushorts (hi+lo) -> end ~39013312 floats (~156.1 MB)
    // aliases:
    //   vT  (256 x 50176 bf16 = 25.7MB) -> znext region (dead until k_znext)
    //   csr_row (800000 ints) -> kpb (dead after k_edge)
    //   vr  (12.8M bf16)      -> qp  (dead after k_edge)
    unsigned short* vT  = (unsigned short*)znext;
    int* csr_row        = (int*)kpb;
    unsigned short* vr  = (unsigned short*)qp;

    hipMemsetAsync(ws + 148480, 0, (size_t)(331840 - 148480)*sizeof(float), stream);
    k_prep<<<128, 256, 0, stream>>>(Wq, Wqb, Wk, Wkb, Wv, Wvb, Wo, proj, Wt, bext, WoT);
    k_prep2<<<512, 256, 0, stream>>>(Wt, Wcb);
    k_ztail<<<88, 256, 0, stream>>>((unsigned*)vT);
    k_qkv_mfma<<<782, 256, 0, stream>>>(z, Wcb, bext, vbuf, qp, kpb, stab);
    k_deg<<<3125, 256, 0, stream>>>(ei, din, dout_);
    k_rs<<<196, 256, 0, stream>>>(dout_, rsd);
    k_scan_part<<<196, 256, 0, stream>>>(din, bsum);
    k_scan_top<<<1, 64, 0, stream>>>(bsum, boff);
    k_scan_fin<<<196, 256, 0, stream>>>(din, boff, offsets, cursor);
    k_kp<<<512, 256, 0, stream>>>(kpb, stab, kp_sum);
    k_vt<<<dim3(782, 4), 256, 0, stream>>>(vbuf, vT);
    k_kvs<<<dim3(KVSNB, 4), 256, 0, stream>>>(kpb, g, vT, kvs, ktg);
    k_znext<<<dim3(196,4), 256, 0, stream>>>(qp, kvs, ktg, kp_sum, znext);
    k_edge<<<12500, 256, 0, stream>>>(ei, qp, kpb, A);
    k_scatter<<<3125, 256, 0, stream>>>(ei, cursor, csr_row);       // csr_row aliases kpb (dead now)
    k_vr<<<12500, 256, 0, stream>>>(vbuf, rsd, vr);                 // vr aliases qp (dead now)
    k_conv_csr<<<12500, 256, 0, stream>>>(offsets, csr_row, din, vr, brb, znext);
    k_out<<<196, 256, 0, stream>>>(znext, WoT, Wob, out);
}